// Round 15
// baseline (111.045 us; speedup 1.0000x reference)
//
#include <hip/hip_runtime.h>

#define XOR16(v)     __shfl_xor((v), 16, 64)
#define FENCE() asm volatile("" ::: "memory")
#define SB() __builtin_amdgcn_sched_barrier(0)

// per-item LDS layout (dwords). 2 items per 64-thread (1-wave) block;
// 32 lanes/item for the fp32 phases: lane (r,h) owns cols [8h..8h+7] of row r.
// Phase 2 (Pp) runs as 3 MFMAs/item using all 64 lanes.
#define STR    1932
#define OFF_M1    0    // Pp -> Pn (16 rows x 20) = 320
#define OFF_M2  320    // A fp32 (15x20); after ph1: PpCt cols0-5 / K cols8-13 per row
#define OFF_C   620    // C (6x16, col15 = 0)
#define OFF_S4  716    // B fp32 (15x8; dword6 = xp stage)
#define OFF_R   836    // R (6x8)
#define OFF_VX  884    // x vector -> ev (16)
#define OFF_VU  900    // u vector (8)
#define OFF_GB  908    // Gbf = [A|0|B|0] 16x40 bf16 (320 dw)
#define OFF_HB  1228   // Hbf = blockdiag(P,Q) 32x40 bf16 (640 dw); YT fp32 32x20 overlays
#define OFF_SS  1868   // S (6x8) = 48  (inside the zeroed GB..STR region)

using bf16x8 = __attribute__((ext_vector_type(8))) short;
using f32x4  = __attribute__((ext_vector_type(4))) float;

__device__ __forceinline__ unsigned short f2bf(float f) {
    union { float f; unsigned u; } v; v.f = f;
    unsigned r = v.u + 0x7FFFu + ((v.u >> 16) & 1u);   // RNE
    return (unsigned short)(r >> 16);
}
__device__ __forceinline__ float dot8(const float* Lr, const float* v) {
    float4 x0 = *(const float4*)(Lr);
    float4 x1 = *(const float4*)(Lr + 4);
    return v[0]*x0.x + v[1]*x0.y + v[2]*x0.z + v[3]*x0.w
         + v[4]*x1.x + v[5]*x1.y + v[6]*x1.z + v[7]*x1.w;
}
__device__ __forceinline__ void rd8(const float* Lr, float* v) {
    float4 x0 = *(const float4*)(Lr);
    float4 x1 = *(const float4*)(Lr + 4);
    v[0]=x0.x; v[1]=x0.y; v[2]=x0.z; v[3]=x0.w;
    v[4]=x1.x; v[5]=x1.y; v[6]=x1.z; v[7]=x1.w;
}
__device__ __forceinline__ float dot6(const float* Lr, const float* v) {
    float4 x0 = *(const float4*)(Lr);
    float2 x1 = *(const float2*)(Lr + 4);
    return v[0]*x0.x + v[1]*x0.y + v[2]*x0.z + v[3]*x0.w + v[4]*x1.x + v[5]*x1.y;
}
__device__ __forceinline__ void rd6(const float* Lr, float* v) {
    float4 x0 = *(const float4*)(Lr);
    float2 x1 = *(const float2*)(Lr + 4);
    v[0]=x0.x; v[1]=x0.y; v[2]=x0.z; v[3]=x0.w; v[4]=x1.x; v[5]=x1.y;
}
__device__ __forceinline__ void wrow6(float* Lr, const float* v) {
    *(float4*)(Lr)     = make_float4(v[0],v[1],v[2],v[3]);
    *(float2*)(Lr + 4) = make_float2(v[4],v[5]);
}
__device__ __forceinline__ void wrow8(float* Lr, const float* v) {
    *(float4*)(Lr)     = make_float4(v[0],v[1],v[2],v[3]);
    *(float4*)(Lr + 4) = make_float4(v[4],v[5],v[6],v[7]);
}

__global__
__attribute__((amdgpu_flat_work_group_size(64, 64)))
__attribute__((amdgpu_waves_per_eu(2, 4)))
void ekf_kernel(
    const float* __restrict__ g_state, const float* __restrict__ g_obs,
    const float* __restrict__ g_u,     const float* __restrict__ g_P,
    const float* __restrict__ g_A,     const float* __restrict__ g_B,
    const float* __restrict__ g_C,     const float* __restrict__ g_D,
    const float* __restrict__ g_c1,    const float* __restrict__ g_c2,
    const float* __restrict__ g_Q,     const float* __restrict__ g_R,
    float* __restrict__ o_xp, float* __restrict__ o_Pn, int bn)
{
    __shared__ __align__(16) float lds[2 * STR];
    const int tid = threadIdx.x;        // 64 threads = ONE wave = 2 items
    const int ib0 = blockIdx.x * 2;
    const int nIt = min(2, bn - ib0);

    const int g   = tid >> 5;           // item within block
    const int s   = tid & 31;           // lane within item
    const int r   = s & 15;             // row
    const int h   = s >> 4;             // column half
    const int j0  = 8 * h;
    const int itc = ib0 + ((g < nIt) ? g : (nIt - 1));
    const int rc  = r < 15 ? r : 14;
    const int rc6 = r < 6 ? r : 5;
    float* L = lds + g * STR;

    // ================= staging: ALL global loads issued up-front ==========
    const float* gp = g_P + (size_t)ib0 * 225;
    const float* ga = g_A + (size_t)ib0 * 225;
    const float* gc = g_C + (size_t)ib0 * 90;
    const float* gb = g_B + (size_t)ib0 * 90;
    const float* gq = g_Q + (size_t)ib0 * 36;
    const float* gr = g_R + (size_t)ib0 * 36;
    const float* gs = g_state + (size_t)ib0 * 15;
    const float* gu = g_u + (size_t)ib0 * 6;
    const int limPA = nIt * 225, limCB = nIt * 90, limQR = nIt * 36;
    const int limS = nIt * 15, limU = nIt * 6;

    float vP[8], vA[8], vC[3], vB[3], vQ[2], vR[2], vS, vU;
    #pragma unroll
    for (int t = 0; t < 8; ++t) {
        int i = min(tid + t * 64, limPA - 1);
        vP[t] = gp[i]; vA[t] = ga[i];
    }
    #pragma unroll
    for (int t = 0; t < 3; ++t) {
        int i = min(tid + t * 64, limCB - 1);
        vC[t] = gc[i]; vB[t] = gb[i];
    }
    #pragma unroll
    for (int t = 0; t < 2; ++t) {
        int i = min(tid + t * 64, limQR - 1);
        vQ[t] = gq[i]; vR[t] = gr[i];
    }
    vS = gs[min(tid, limS - 1)];
    vU = gu[min(tid, limU - 1)];
    float c1v  = g_c1[(size_t)itc * 15 + rc];
    float obsv = g_obs[(size_t)itc * 6 + rc6];
    float c2v  = g_c2[(size_t)itc * 6 + rc6];
    const float* Db = g_D + (size_t)itc * 36 + rc6 * 6;
    float dd0 = Db[0], dd1 = Db[1], dd2 = Db[2], dd3 = Db[3], dd4 = Db[4], dd5 = Db[5];

    // ---- zero Gbf/Hbf (+pad) region [OFF_GB, STR) per item ----
    #pragma unroll
    for (int g2 = 0; g2 < 2; ++g2) {
        #pragma unroll
        for (int t = 0; t < 4; ++t)
            *(float4*)(lds + g2 * STR + OFF_GB + t * 256 + tid * 4)
                = make_float4(0.f, 0.f, 0.f, 0.f);
    }
    FENCE();   // order zero-stores before the b16 data stores (TBAA guard)

    // ---- fp32 LDS writes ----
    #pragma unroll
    for (int t = 0; t < 8; ++t) {
        int i = tid + t * 64;
        if (i < 450) {
            int it = i / 225, idx = i - it * 225;
            int rw = idx / 15, j = idx - rw * 15;
            lds[it * STR + OFF_M2 + rw * 20 + j] = vA[t];
        }
    }
    #pragma unroll
    for (int t = 0; t < 3; ++t) {
        int i = tid + t * 64;
        if (i < 180) {
            int it = i / 90, idx = i - it * 90;
            int rw = idx / 15, j = idx - rw * 15;
            lds[it * STR + OFF_C + rw * 16 + j] = vC[t];
            int rb = idx / 6, jb = idx - rb * 6;
            lds[it * STR + OFF_S4 + rb * 8 + jb] = vB[t];
        }
    }
    #pragma unroll
    for (int t = 0; t < 2; ++t) {
        int i = tid + t * 64;
        if (i < 72) {
            int it = i / 36, idx = i - it * 36;
            int rw = idx / 6, j = idx - rw * 6;
            lds[it * STR + OFF_R + rw * 8 + j] = vR[t];
        }
    }
    if (tid < 30) { int it = tid / 15, rw = tid - it * 15; lds[it * STR + OFF_VX + rw] = vS; }
    if (tid < 12) { int it = tid / 6,  rw = tid - it * 6;  lds[it * STR + OFF_VU + rw] = vU; }
    if (s < 6)  L[OFF_C + s * 16 + 15] = 0.f;      // C col-15 pad
    if (s == 15) L[OFF_VX + 15] = 0.f;             // x pad

    // ---- bf16 writes: G = [A | 0 | B | 0], H = blockdiag(P, Q) ----
    {
        unsigned short* lb = (unsigned short*)lds;
        #pragma unroll
        for (int t = 0; t < 8; ++t) {
            int i = tid + t * 64;
            if (i < 450) {
                int it = i / 225, idx = i - it * 225;
                int rw = idx / 15, j = idx - rw * 15;
                lb[(it * STR + OFF_GB) * 2 + rw * 40 + j] = f2bf(vA[t]);
                lb[(it * STR + OFF_HB) * 2 + rw * 40 + j] = f2bf(vP[t]);
            }
        }
        #pragma unroll
        for (int t = 0; t < 3; ++t) {
            int i = tid + t * 64;
            if (i < 180) {
                int it = i / 90, idx = i - it * 90;
                int rb = idx / 6, jb = idx - rb * 6;
                lb[(it * STR + OFF_GB) * 2 + rb * 40 + 16 + jb] = f2bf(vB[t]);
            }
        }
        #pragma unroll
        for (int t = 0; t < 2; ++t) {
            int i = tid + t * 64;
            if (i < 72) {
                int it = i / 36, idx = i - it * 36;
                int rq = idx / 6, cq = idx - rq * 6;
                lb[(it * STR + OFF_HB) * 2 + (16 + rq) * 40 + 16 + cq] = f2bf(vQ[t]);
            }
        }
    }
    FENCE(); SB();

    // ================= phase 1: xp0, ev (half-dots + xor-sum) =============
    float xp;
    {
        float xh[8]; rd8(L + OFF_VX + j0, xh);
        float u6[6]; rd6(L + OFF_VU, u6);
        float xpp =  dot8(L + OFF_M2 + rc * 20 + j0, xh);
        float evp = -dot8(L + OFF_C + rc6 * 16 + j0, xh);
        if (h == 0) {
            xpp += c1v + dot6(L + OFF_S4 + rc * 8, u6);
            evp += obsv - c2v
                 - (dd0*u6[0] + dd1*u6[1] + dd2*u6[2]
                  + dd3*u6[3] + dd4*u6[4] + dd5*u6[5]);
        }
        xp = xpp + XOR16(xpp);
        float ev = evp + XOR16(evp);
        FENCE();
        if (h == 0 && r < 6) L[OFF_VX + r] = ev;   // stage ev (x dead)
        FENCE();
    }
    SB();

    // ============ phase 2: Pp = G H G^T via MFMA (bf16, fp32 acc) =========
    // Y' = G@H (two 16-col slabs); Pp = Y'@G^T. H, Pp symmetric.
    const int q  = tid >> 4;          // k-group / D-row group (0..3)
    const int cL = tid & 15;          // A-row / B,D-col index
    {
        char* lb = (char*)lds;
        bf16x8 ga0  = *(bf16x8*)(lb + (0*STR + OFF_GB)*4 + cL*80 + q*16);
        bf16x8 ga1  = *(bf16x8*)(lb + (1*STR + OFF_GB)*4 + cL*80 + q*16);
        bf16x8 hb00 = *(bf16x8*)(lb + (0*STR + OFF_HB)*4 + cL*80 + q*16);
        bf16x8 hb01 = *(bf16x8*)(lb + (0*STR + OFF_HB)*4 + (16+cL)*80 + q*16);
        bf16x8 hb10 = *(bf16x8*)(lb + (1*STR + OFF_HB)*4 + cL*80 + q*16);
        bf16x8 hb11 = *(bf16x8*)(lb + (1*STR + OFF_HB)*4 + (16+cL)*80 + q*16);
        f32x4 z = {0.f, 0.f, 0.f, 0.f};
        f32x4 y00 = __builtin_amdgcn_mfma_f32_16x16x32_bf16(ga0, hb00, z, 0, 0, 0);
        f32x4 y01 = __builtin_amdgcn_mfma_f32_16x16x32_bf16(ga0, hb01, z, 0, 0, 0);
        f32x4 y10 = __builtin_amdgcn_mfma_f32_16x16x32_bf16(ga1, hb10, z, 0, 0, 0);
        f32x4 y11 = __builtin_amdgcn_mfma_f32_16x16x32_bf16(ga1, hb11, z, 0, 0, 0);
        FENCE();
        // stage Y'^T (fp32) over Hbf: lane's D col-segment -> YT[col][4q..4q+3]
        *(f32x4*)(lds + 0*STR + OFF_HB + cL*20 + 4*q)        = y00;
        *(f32x4*)(lds + 0*STR + OFF_HB + (16 + cL)*20 + 4*q) = y01;
        *(f32x4*)(lds + 1*STR + OFF_HB + cL*20 + 4*q)        = y10;
        *(f32x4*)(lds + 1*STR + OFF_HB + (16 + cL)*20 + 4*q) = y11;
        FENCE(); SB();
        // A-frag of Y': lane needs Y'[cL][8q+j] = YT[8q+j][cL]
        bf16x8 ya0, ya1;
        #pragma unroll
        for (int j = 0; j < 8; ++j) {
            float a0 = lds[0*STR + OFF_HB + (8*q + j)*20 + cL];
            float a1 = lds[1*STR + OFF_HB + (8*q + j)*20 + cL];
            ya0[j] = (short)f2bf(a0);
            ya1[j] = (short)f2bf(a1);
        }
        SB();
        f32x4 pp0 = __builtin_amdgcn_mfma_f32_16x16x32_bf16(ya0, ga0, z, 0, 0, 0);
        f32x4 pp1 = __builtin_amdgcn_mfma_f32_16x16x32_bf16(ya1, ga1, z, 0, 0, 0);
        FENCE();
        // Pp symmetric: D col-segment (rows 4q..4q+3, col cL) == row cL, cols 4q..4q+3
        *(f32x4*)(lds + 0*STR + OFF_M1 + cL*20 + 4*q) = pp0;
        *(f32x4*)(lds + 1*STR + OFF_M1 + cL*20 + 4*q) = pp1;
        FENCE(); SB();
    }

    // ================= phase 3: K (Cholesky in registers) =================
    float pp8[8];
    rd8(L + OFF_M1 + rc * 20 + j0, pp8);   // my Pp row half (col15 pad = ~0)
    SB();
    float ppct[6];
    {
        #define PCJ(c) ppct[(c)] = dot8(L + OFF_C + (c)*16 + j0, pp8)
        PCJ(0); PCJ(1); PCJ(2); SB(); PCJ(3); PCJ(4); PCJ(5); SB();
        #pragma unroll
        for (int c = 0; c < 6; ++c) ppct[c] += XOR16(ppct[c]);
    }
    FENCE();
    if (h == 0 && r < 15) wrow6(L + OFF_M2 + r * 20, ppct);  // PpCt -> M2 cols 0-5 (A dead)
    FENCE(); SB();

    float kk[6];
    {
        // S = C @ PpCt + R, distributed over k-halves
        float sm[6];
        #pragma unroll
        for (int c = 0; c < 6; ++c) sm[c] = 0.f;
        {
            float ch[8]; rd8(L + OFF_C + rc6 * 16 + j0, ch);
            #define SAK(k) do { float pr[6]; rd6(L + OFF_M2 + min(j0 + (k), 14)*20, pr); \
                float cv = ch[(k)]; \
                sm[0]+=cv*pr[0]; sm[1]+=cv*pr[1]; sm[2]+=cv*pr[2]; \
                sm[3]+=cv*pr[3]; sm[4]+=cv*pr[4]; sm[5]+=cv*pr[5]; } while(0)
            SAK(0); SAK(1); SAK(2); SAK(3); SB();
            SAK(4); SAK(5); SAK(6); SAK(7); SB();
        }
        #pragma unroll
        for (int c = 0; c < 6; ++c) sm[c] += XOR16(sm[c]);
        if (h == 0 && r < 6) {
            float rr6[6]; rd6(L + OFF_R + r * 8, rr6);
            float srow[6];
            #pragma unroll
            for (int c = 0; c < 6; ++c) srow[c] = sm[c] + rr6[c];
            wrow6(L + OFF_SS + r * 8, srow);                // S -> SS
        }
        FENCE(); SB();

        // uniform broadcast read of S (lower triangle used)
        float r0[6], r1[6], r2[6], r3[6], r4[6], r5[6];
        rd6(L + OFF_SS + 0*8, r0); rd6(L + OFF_SS + 1*8, r1); rd6(L + OFF_SS + 2*8, r2); SB();
        rd6(L + OFF_SS + 3*8, r3); rd6(L + OFF_SS + 4*8, r4); rd6(L + OFF_SS + 5*8, r5); SB();

        // Cholesky S = L L^T (registers only; S SPD, diag >= 0.1)
        float l00 = sqrtf(r0[0]);                 float i0 = 1.f / l00;
        float l10 = r1[0]*i0, l20 = r2[0]*i0, l30 = r3[0]*i0, l40 = r4[0]*i0, l50 = r5[0]*i0;
        float l11 = sqrtf(r1[1] - l10*l10);       float i1 = 1.f / l11;
        float l21 = (r2[1] - l20*l10)*i1;
        float l31 = (r3[1] - l30*l10)*i1;
        float l41 = (r4[1] - l40*l10)*i1;
        float l51 = (r5[1] - l50*l10)*i1;
        float l22 = sqrtf(r2[2] - l20*l20 - l21*l21); float i2 = 1.f / l22;
        float l32 = (r3[2] - l30*l20 - l31*l21)*i2;
        float l42 = (r4[2] - l40*l20 - l41*l21)*i2;
        float l52 = (r5[2] - l50*l20 - l51*l21)*i2;
        float l33 = sqrtf(r3[3] - l30*l30 - l31*l31 - l32*l32); float i3 = 1.f / l33;
        float l43 = (r4[3] - l40*l30 - l41*l31 - l42*l32)*i3;
        float l53 = (r5[3] - l50*l30 - l51*l31 - l52*l32)*i3;
        float l44 = sqrtf(r4[4] - l40*l40 - l41*l41 - l42*l42 - l43*l43); float i4 = 1.f / l44;
        float l54 = (r5[4] - l50*l40 - l51*l41 - l52*l42 - l53*l43)*i4;
        float l55 = sqrtf(r5[5] - l50*l50 - l51*l51 - l52*l52 - l53*l53 - l54*l54);
        float i5 = 1.f / l55;

        // solve S x = ppct; kk = K row rc
        float y0 =  ppct[0]*i0;
        float y1 = (ppct[1] - l10*y0)*i1;
        float y2 = (ppct[2] - l20*y0 - l21*y1)*i2;
        float y3 = (ppct[3] - l30*y0 - l31*y1 - l32*y2)*i3;
        float y4 = (ppct[4] - l40*y0 - l41*y1 - l42*y2 - l43*y3)*i4;
        float y5 = (ppct[5] - l50*y0 - l51*y1 - l52*y2 - l53*y3 - l54*y4)*i5;
        kk[5] =  y5*i5;
        kk[4] = (y4 - l54*kk[5])*i4;
        kk[3] = (y3 - l43*kk[4] - l53*kk[5])*i3;
        kk[2] = (y2 - l32*kk[3] - l42*kk[4] - l52*kk[5])*i2;
        kk[1] = (y1 - l21*kk[2] - l31*kk[3] - l41*kk[4] - l51*kk[5])*i1;
        kk[0] = (y0 - l10*kk[1] - l20*kk[2] - l30*kk[3] - l40*kk[4] - l50*kk[5])*i0;
    }
    FENCE();
    if (h == 0 && r < 15) wrow6(L + OFF_M2 + r * 20 + 8, kk);  // K -> M2 cols 8-13
    FENCE();
    {   // xp += K e  (ev staged in OFF_VX)
        float e6[6]; rd6(L + OFF_VX, e6);
        xp += kk[0]*e6[0] + kk[1]*e6[1] + kk[2]*e6[2]
            + kk[3]*e6[3] + kk[4]*e6[4] + kk[5]*e6[5];
    }
    SB();

    // ===== phase 4: T3 = Pp - K*PpCt^T; Pn = T3 + (K*R - T3*C^T)*K^T ======
    float pn8[8];
    {
        float t38[8];
        #define T3J(j) do { float pr[6]; rd6(L + OFF_M2 + min(j0 + (j), 14)*20, pr); \
            t38[(j)] = pp8[(j)] - (kk[0]*pr[0]+kk[1]*pr[1]+kk[2]*pr[2] \
                                  +kk[3]*pr[3]+kk[4]*pr[4]+kk[5]*pr[5]); } while(0)
        T3J(0); T3J(1); T3J(2); T3J(3); SB();
        T3J(4); T3J(5); T3J(6); T3J(7); SB();
        if (j0 + 7 >= 15) t38[7] = 0.f;

        float w[6];
        #define GJ(c) w[(c)] = dot8(L + OFF_C + (c)*16 + j0, t38)
        GJ(0); GJ(1); GJ(2); SB(); GJ(3); GJ(4); GJ(5); SB();
        #pragma unroll
        for (int c = 0; c < 6; ++c) w[c] = -(w[c] + XOR16(w[c]));

        #define KRK(k) do { float rk[6]; rd6(L + OFF_R + (k)*8, rk); \
            w[0]+=kk[(k)]*rk[0]; w[1]+=kk[(k)]*rk[1]; w[2]+=kk[(k)]*rk[2]; \
            w[3]+=kk[(k)]*rk[3]; w[4]+=kk[(k)]*rk[4]; w[5]+=kk[(k)]*rk[5]; } while(0)
        KRK(0); KRK(1); KRK(2); SB(); KRK(3); KRK(4); KRK(5); SB();

        #define PNJ(j) do { float krow[6]; rd6(L + OFF_M2 + min(j0 + (j), 14)*20 + 8, krow); \
            pn8[(j)] = t38[(j)] + (w[0]*krow[0]+w[1]*krow[1]+w[2]*krow[2] \
                                  +w[3]*krow[3]+w[4]*krow[4]+w[5]*krow[5]); } while(0)
        PNJ(0); PNJ(1); PNJ(2); PNJ(3); SB();
        PNJ(4); PNJ(5); PNJ(6); PNJ(7); SB();
        if (j0 + 7 >= 15) pn8[7] = 0.f;
    }

    // ---- stage results: Pn -> M1, xp -> S4 dword 6 ----
    FENCE();
    if (r < 15) {
        wrow8(L + OFF_M1 + rc * 20 + j0, pn8);
        if (h == 0) L[OFF_S4 + r * 8 + 6] = xp;
    }
    FENCE(); SB();

    // ---- coalesced stores (unrolled) ----
    {
        float* gpn = o_Pn + (size_t)ib0 * 225;
        float sP[8];
        #pragma unroll
        for (int t = 0; t < 8; ++t) {
            int i = min(tid + t * 64, 449);
            int it = i / 225, idx = i - it * 225;
            int rw = idx / 15, j = idx - rw * 15;
            sP[t] = lds[it * STR + OFF_M1 + rw * 20 + j];
        }
        #pragma unroll
        for (int t = 0; t < 8; ++t) {
            int i = tid + t * 64;
            if (i < limPA) gpn[i] = sP[t];
        }
        float* gxp = o_xp + (size_t)ib0 * 15;
        if (tid < limS) {
            int it = tid / 15, rw = tid - it * 15;
            gxp[tid] = lds[it * STR + OFF_S4 + rw * 8 + 6];
        }
    }
}

extern "C" void kernel_launch(void* const* d_in, const int* in_sizes, int n_in,
                              void* d_out, int out_size, void* d_ws, size_t ws_size,
                              hipStream_t stream) {
    const float* g_state = (const float*)d_in[0];
    const float* g_obs   = (const float*)d_in[1];
    const float* g_u     = (const float*)d_in[2];
    const float* g_P     = (const float*)d_in[3];
    const float* g_A     = (const float*)d_in[4];
    const float* g_B     = (const float*)d_in[5];
    const float* g_C     = (const float*)d_in[6];
    const float* g_D     = (const float*)d_in[7];
    const float* g_c1    = (const float*)d_in[8];
    const float* g_c2    = (const float*)d_in[9];
    const float* g_Q     = (const float*)d_in[10];
    const float* g_R     = (const float*)d_in[11];

    const int bn = in_sizes[0] / 15;
    float* o_xp = (float*)d_out;
    float* o_pn = o_xp + (size_t)bn * 15;

    const int blocks = (bn + 1) / 2;   // 2 items per 64-thread (1-wave) block
    ekf_kernel<<<blocks, 64, 0, stream>>>(
        g_state, g_obs, g_u, g_P, g_A, g_B, g_C, g_D, g_c1, g_c2, g_Q, g_R,
        o_xp, o_pn, bn);
}

// Round 16
// 110.512 us; speedup vs baseline: 1.0048x; 1.0048x over previous
//
#include <hip/hip_runtime.h>

#define XOR16(v)     __shfl_xor((v), 16, 64)
#define FENCE() asm volatile("" ::: "memory")
#define SB() __builtin_amdgcn_sched_barrier(0)

// per-item LDS layout (dwords). 2 items per 64-thread (1-wave) block;
// 32 lanes/item for the fp32 phases: lane (r,h) owns cols [8h..8h+7] of row r.
// Phase 2 (Pp = G H G^T) runs as 3 MFMAs/item using all 64 lanes:
//   Z = H G^T  (H symmetric -> A-frag = H rows; B-frag = G rows)
//   W = Z^T stored bf16 (convert-before-store; D col-segments become W rows)
//   Pp = G Z   (A-frag = G rows; B-frag = W rows, contiguous b128)
#define STR    1932
#define OFF_M1    0    // Pp -> Pn (16 rows x 20) = 320
#define OFF_M2  320    // A fp32 (15x20); after ph1: PpCt cols0-5 / K cols8-13 per row
#define OFF_C   620    // C (6x16, col15 = 0)
#define OFF_S4  716    // B fp32 (15x8; dword6 = xp stage)
#define OFF_R   836    // R (6x8)
#define OFF_VX  884    // x vector -> ev (16)
#define OFF_VU  900    // u vector (8)
#define OFF_GB  908    // Gbf = [A|0|B|0] 16x40 bf16 (320 dw)
#define OFF_HB  1228   // Hbf = blockdiag(P,Q) 32x40 bf16 (640 dw); W bf16 16x40 overlays rows 0..15
#define OFF_SS  1868   // S (6x8) = 48  (inside the zeroed GB..STR region)

using bf16x8 = __attribute__((ext_vector_type(8))) short;
using f32x4  = __attribute__((ext_vector_type(4))) float;

__device__ __forceinline__ unsigned short f2bf(float f) {
    union { float f; unsigned u; } v; v.f = f;
    unsigned r = v.u + 0x7FFFu + ((v.u >> 16) & 1u);   // RNE
    return (unsigned short)(r >> 16);
}
__device__ __forceinline__ float dot8(const float* Lr, const float* v) {
    float4 x0 = *(const float4*)(Lr);
    float4 x1 = *(const float4*)(Lr + 4);
    return v[0]*x0.x + v[1]*x0.y + v[2]*x0.z + v[3]*x0.w
         + v[4]*x1.x + v[5]*x1.y + v[6]*x1.z + v[7]*x1.w;
}
__device__ __forceinline__ void rd8(const float* Lr, float* v) {
    float4 x0 = *(const float4*)(Lr);
    float4 x1 = *(const float4*)(Lr + 4);
    v[0]=x0.x; v[1]=x0.y; v[2]=x0.z; v[3]=x0.w;
    v[4]=x1.x; v[5]=x1.y; v[6]=x1.z; v[7]=x1.w;
}
__device__ __forceinline__ float dot6(const float* Lr, const float* v) {
    float4 x0 = *(const float4*)(Lr);
    float2 x1 = *(const float2*)(Lr + 4);
    return v[0]*x0.x + v[1]*x0.y + v[2]*x0.z + v[3]*x0.w + v[4]*x1.x + v[5]*x1.y;
}
__device__ __forceinline__ void rd6(const float* Lr, float* v) {
    float4 x0 = *(const float4*)(Lr);
    float2 x1 = *(const float2*)(Lr + 4);
    v[0]=x0.x; v[1]=x0.y; v[2]=x0.z; v[3]=x0.w; v[4]=x1.x; v[5]=x1.y;
}
__device__ __forceinline__ void wrow6(float* Lr, const float* v) {
    *(float4*)(Lr)     = make_float4(v[0],v[1],v[2],v[3]);
    *(float2*)(Lr + 4) = make_float2(v[4],v[5]);
}
__device__ __forceinline__ void wrow8(float* Lr, const float* v) {
    *(float4*)(Lr)     = make_float4(v[0],v[1],v[2],v[3]);
    *(float4*)(Lr + 4) = make_float4(v[4],v[5],v[6],v[7]);
}

__global__
__attribute__((amdgpu_flat_work_group_size(64, 64)))
__attribute__((amdgpu_waves_per_eu(2, 4)))
void ekf_kernel(
    const float* __restrict__ g_state, const float* __restrict__ g_obs,
    const float* __restrict__ g_u,     const float* __restrict__ g_P,
    const float* __restrict__ g_A,     const float* __restrict__ g_B,
    const float* __restrict__ g_C,     const float* __restrict__ g_D,
    const float* __restrict__ g_c1,    const float* __restrict__ g_c2,
    const float* __restrict__ g_Q,     const float* __restrict__ g_R,
    float* __restrict__ o_xp, float* __restrict__ o_Pn, int bn)
{
    __shared__ __align__(16) float lds[2 * STR];
    const int tid = threadIdx.x;        // 64 threads = ONE wave = 2 items
    const int ib0 = blockIdx.x * 2;
    const int nIt = min(2, bn - ib0);

    const int g   = tid >> 5;           // item within block
    const int s   = tid & 31;           // lane within item
    const int r   = s & 15;             // row
    const int h   = s >> 4;             // column half
    const int j0  = 8 * h;
    const int itc = ib0 + ((g < nIt) ? g : (nIt - 1));
    const int rc  = r < 15 ? r : 14;
    const int rc6 = r < 6 ? r : 5;
    float* L = lds + g * STR;

    // ================= staging: ALL global loads issued up-front ==========
    const float* gp = g_P + (size_t)ib0 * 225;
    const float* ga = g_A + (size_t)ib0 * 225;
    const float* gc = g_C + (size_t)ib0 * 90;
    const float* gb = g_B + (size_t)ib0 * 90;
    const float* gq = g_Q + (size_t)ib0 * 36;
    const float* gr = g_R + (size_t)ib0 * 36;
    const float* gs = g_state + (size_t)ib0 * 15;
    const float* gu = g_u + (size_t)ib0 * 6;
    const int limPA = nIt * 225, limCB = nIt * 90, limQR = nIt * 36;
    const int limS = nIt * 15, limU = nIt * 6;

    float vP[8], vA[8], vC[3], vB[3], vQ[2], vR[2], vS, vU;
    #pragma unroll
    for (int t = 0; t < 8; ++t) {
        int i = min(tid + t * 64, limPA - 1);
        vP[t] = gp[i]; vA[t] = ga[i];
    }
    #pragma unroll
    for (int t = 0; t < 3; ++t) {
        int i = min(tid + t * 64, limCB - 1);
        vC[t] = gc[i]; vB[t] = gb[i];
    }
    #pragma unroll
    for (int t = 0; t < 2; ++t) {
        int i = min(tid + t * 64, limQR - 1);
        vQ[t] = gq[i]; vR[t] = gr[i];
    }
    vS = gs[min(tid, limS - 1)];
    vU = gu[min(tid, limU - 1)];
    float c1v  = g_c1[(size_t)itc * 15 + rc];
    float obsv = g_obs[(size_t)itc * 6 + rc6];
    float c2v  = g_c2[(size_t)itc * 6 + rc6];
    const float* Db = g_D + (size_t)itc * 36 + rc6 * 6;
    float dd0 = Db[0], dd1 = Db[1], dd2 = Db[2], dd3 = Db[3], dd4 = Db[4], dd5 = Db[5];

    // ---- zero Gbf/Hbf (+pad) region [OFF_GB, STR) per item ----
    #pragma unroll
    for (int g2 = 0; g2 < 2; ++g2) {
        #pragma unroll
        for (int t = 0; t < 4; ++t)
            *(float4*)(lds + g2 * STR + OFF_GB + t * 256 + tid * 4)
                = make_float4(0.f, 0.f, 0.f, 0.f);
    }
    FENCE();   // order zero-stores before the b16 data stores

    // ---- fp32 LDS writes ----
    #pragma unroll
    for (int t = 0; t < 8; ++t) {
        int i = tid + t * 64;
        if (i < 450) {
            int it = i / 225, idx = i - it * 225;
            int rw = idx / 15, j = idx - rw * 15;
            lds[it * STR + OFF_M2 + rw * 20 + j] = vA[t];
        }
    }
    #pragma unroll
    for (int t = 0; t < 3; ++t) {
        int i = tid + t * 64;
        if (i < 180) {
            int it = i / 90, idx = i - it * 90;
            int rw = idx / 15, j = idx - rw * 15;
            lds[it * STR + OFF_C + rw * 16 + j] = vC[t];
            int rb = idx / 6, jb = idx - rb * 6;
            lds[it * STR + OFF_S4 + rb * 8 + jb] = vB[t];
        }
    }
    #pragma unroll
    for (int t = 0; t < 2; ++t) {
        int i = tid + t * 64;
        if (i < 72) {
            int it = i / 36, idx = i - it * 36;
            int rw = idx / 6, j = idx - rw * 6;
            lds[it * STR + OFF_R + rw * 8 + j] = vR[t];
        }
    }
    if (tid < 30) { int it = tid / 15, rw = tid - it * 15; lds[it * STR + OFF_VX + rw] = vS; }
    if (tid < 12) { int it = tid / 6,  rw = tid - it * 6;  lds[it * STR + OFF_VU + rw] = vU; }
    if (s < 6)  L[OFF_C + s * 16 + 15] = 0.f;      // C col-15 pad
    if (s == 15) L[OFF_VX + 15] = 0.f;             // x pad

    // ---- bf16 writes: G = [A | 0 | B | 0], H = blockdiag(P, Q) ----
    {
        unsigned short* lb = (unsigned short*)lds;
        #pragma unroll
        for (int t = 0; t < 8; ++t) {
            int i = tid + t * 64;
            if (i < 450) {
                int it = i / 225, idx = i - it * 225;
                int rw = idx / 15, j = idx - rw * 15;
                lb[(it * STR + OFF_GB) * 2 + rw * 40 + j] = f2bf(vA[t]);
                lb[(it * STR + OFF_HB) * 2 + rw * 40 + j] = f2bf(vP[t]);
            }
        }
        #pragma unroll
        for (int t = 0; t < 3; ++t) {
            int i = tid + t * 64;
            if (i < 180) {
                int it = i / 90, idx = i - it * 90;
                int rb = idx / 6, jb = idx - rb * 6;
                lb[(it * STR + OFF_GB) * 2 + rb * 40 + 16 + jb] = f2bf(vB[t]);
            }
        }
        #pragma unroll
        for (int t = 0; t < 2; ++t) {
            int i = tid + t * 64;
            if (i < 72) {
                int it = i / 36, idx = i - it * 36;
                int rq = idx / 6, cq = idx - rq * 6;
                lb[(it * STR + OFF_HB) * 2 + (16 + rq) * 40 + 16 + cq] = f2bf(vQ[t]);
            }
        }
    }
    FENCE(); SB();

    // ================= phase 1: xp0, ev (half-dots + xor-sum) =============
    float xp;
    {
        float xh[8]; rd8(L + OFF_VX + j0, xh);
        float u6[6]; rd6(L + OFF_VU, u6);
        float xpp =  dot8(L + OFF_M2 + rc * 20 + j0, xh);
        float evp = -dot8(L + OFF_C + rc6 * 16 + j0, xh);
        if (h == 0) {
            xpp += c1v + dot6(L + OFF_S4 + rc * 8, u6);
            evp += obsv - c2v
                 - (dd0*u6[0] + dd1*u6[1] + dd2*u6[2]
                  + dd3*u6[3] + dd4*u6[4] + dd5*u6[5]);
        }
        xp = xpp + XOR16(xpp);
        float ev = evp + XOR16(evp);
        FENCE();
        if (h == 0 && r < 6) L[OFF_VX + r] = ev;   // stage ev (x dead)
        FENCE();
    }
    SB();

    // ============ phase 2: Pp = G H G^T via MFMA (bf16, fp32 acc) =========
    // Z = H G^T (two 16-row slabs); W = Z^T (bf16, convert-before-store);
    // Pp = G Z (B-frag = W rows, contiguous). H, Pp symmetric.
    const int q  = tid >> 4;          // k-group / D-row group (0..3)
    const int cL = tid & 15;          // row / col index within fragment
    {
        char* lb = (char*)lds;
        bf16x8 ga0 = *(bf16x8*)(lb + (0*STR + OFF_GB)*4 + cL*80 + q*16);
        bf16x8 ga1 = *(bf16x8*)(lb + (1*STR + OFF_GB)*4 + cL*80 + q*16);
        bf16x8 ht0 = *(bf16x8*)(lb + (0*STR + OFF_HB)*4 + cL*80 + q*16);
        bf16x8 hb0 = *(bf16x8*)(lb + (0*STR + OFF_HB)*4 + (16+cL)*80 + q*16);
        bf16x8 ht1 = *(bf16x8*)(lb + (1*STR + OFF_HB)*4 + cL*80 + q*16);
        bf16x8 hb1 = *(bf16x8*)(lb + (1*STR + OFF_HB)*4 + (16+cL)*80 + q*16);
        f32x4 z = {0.f, 0.f, 0.f, 0.f};
        // Z slabs: A = H rows (symmetric), B = G^T (B-frag == G rows == ga)
        f32x4 zt0 = __builtin_amdgcn_mfma_f32_16x16x32_bf16(ht0, ga0, z, 0, 0, 0);
        f32x4 zb0 = __builtin_amdgcn_mfma_f32_16x16x32_bf16(hb0, ga0, z, 0, 0, 0);
        f32x4 zt1 = __builtin_amdgcn_mfma_f32_16x16x32_bf16(ht1, ga1, z, 0, 0, 0);
        f32x4 zb1 = __builtin_amdgcn_mfma_f32_16x16x32_bf16(hb1, ga1, z, 0, 0, 0);
        FENCE();
        // W = Z^T bf16 over Hbf rows 0..15: lane's D col-segment -> W row cL
        // top slab -> W[cL][4q..4q+3], bottom -> W[cL][16+4q..16+4q+3]
        {
            unsigned t0 = (unsigned)f2bf(zt0[0]) | ((unsigned)f2bf(zt0[1]) << 16);
            unsigned t1 = (unsigned)f2bf(zt0[2]) | ((unsigned)f2bf(zt0[3]) << 16);
            unsigned b0 = (unsigned)f2bf(zb0[0]) | ((unsigned)f2bf(zb0[1]) << 16);
            unsigned b1 = (unsigned)f2bf(zb0[2]) | ((unsigned)f2bf(zb0[3]) << 16);
            *(uint2*)(lb + (0*STR + OFF_HB)*4 + cL*80 + 8*q)      = make_uint2(t0, t1);
            *(uint2*)(lb + (0*STR + OFF_HB)*4 + cL*80 + 32 + 8*q) = make_uint2(b0, b1);
            unsigned u0 = (unsigned)f2bf(zt1[0]) | ((unsigned)f2bf(zt1[1]) << 16);
            unsigned u1 = (unsigned)f2bf(zt1[2]) | ((unsigned)f2bf(zt1[3]) << 16);
            unsigned v0 = (unsigned)f2bf(zb1[0]) | ((unsigned)f2bf(zb1[1]) << 16);
            unsigned v1 = (unsigned)f2bf(zb1[2]) | ((unsigned)f2bf(zb1[3]) << 16);
            *(uint2*)(lb + (1*STR + OFF_HB)*4 + cL*80 + 8*q)      = make_uint2(u0, u1);
            *(uint2*)(lb + (1*STR + OFF_HB)*4 + cL*80 + 32 + 8*q) = make_uint2(v0, v1);
        }
        FENCE(); SB();
        // Pp = G Z: A-frag = ga, B-frag = Z[8q+j][cL] = W[cL][8q+j] (b128 read)
        bf16x8 w0 = *(bf16x8*)(lb + (0*STR + OFF_HB)*4 + cL*80 + 16*q);
        bf16x8 w1 = *(bf16x8*)(lb + (1*STR + OFF_HB)*4 + cL*80 + 16*q);
        f32x4 pp0 = __builtin_amdgcn_mfma_f32_16x16x32_bf16(ga0, w0, z, 0, 0, 0);
        f32x4 pp1 = __builtin_amdgcn_mfma_f32_16x16x32_bf16(ga1, w1, z, 0, 0, 0);
        FENCE();
        // Pp symmetric: D col-segment (rows 4q..4q+3, col cL) == row cL, cols 4q..4q+3
        *(f32x4*)(lds + 0*STR + OFF_M1 + cL*20 + 4*q) = pp0;
        *(f32x4*)(lds + 1*STR + OFF_M1 + cL*20 + 4*q) = pp1;
        FENCE(); SB();
    }

    // ================= phase 3: K (Cholesky in registers) =================
    float pp8[8];
    rd8(L + OFF_M1 + rc * 20 + j0, pp8);   // my Pp row half (col15 pad = ~0)
    SB();
    float ppct[6];
    {
        #define PCJ(c) ppct[(c)] = dot8(L + OFF_C + (c)*16 + j0, pp8)
        PCJ(0); PCJ(1); PCJ(2); SB(); PCJ(3); PCJ(4); PCJ(5); SB();
        #pragma unroll
        for (int c = 0; c < 6; ++c) ppct[c] += XOR16(ppct[c]);
    }
    FENCE();
    if (h == 0 && r < 15) wrow6(L + OFF_M2 + r * 20, ppct);  // PpCt -> M2 cols 0-5 (A dead)
    FENCE(); SB();

    float kk[6];
    {
        // S = C @ PpCt + R, distributed over k-halves
        float sm[6];
        #pragma unroll
        for (int c = 0; c < 6; ++c) sm[c] = 0.f;
        {
            float ch[8]; rd8(L + OFF_C + rc6 * 16 + j0, ch);
            #define SAK(k) do { float pr[6]; rd6(L + OFF_M2 + min(j0 + (k), 14)*20, pr); \
                float cv = ch[(k)]; \
                sm[0]+=cv*pr[0]; sm[1]+=cv*pr[1]; sm[2]+=cv*pr[2]; \
                sm[3]+=cv*pr[3]; sm[4]+=cv*pr[4]; sm[5]+=cv*pr[5]; } while(0)
            SAK(0); SAK(1); SAK(2); SAK(3); SB();
            SAK(4); SAK(5); SAK(6); SAK(7); SB();
        }
        #pragma unroll
        for (int c = 0; c < 6; ++c) sm[c] += XOR16(sm[c]);
        if (h == 0 && r < 6) {
            float rr6[6]; rd6(L + OFF_R + r * 8, rr6);
            float srow[6];
            #pragma unroll
            for (int c = 0; c < 6; ++c) srow[c] = sm[c] + rr6[c];
            wrow6(L + OFF_SS + r * 8, srow);                // S -> SS
        }
        FENCE(); SB();

        // uniform broadcast read of S (lower triangle used)
        float r0[6], r1[6], r2[6], r3[6], r4[6], r5[6];
        rd6(L + OFF_SS + 0*8, r0); rd6(L + OFF_SS + 1*8, r1); rd6(L + OFF_SS + 2*8, r2); SB();
        rd6(L + OFF_SS + 3*8, r3); rd6(L + OFF_SS + 4*8, r4); rd6(L + OFF_SS + 5*8, r5); SB();

        // Cholesky S = L L^T (registers only; S SPD, diag >= 0.1)
        float l00 = sqrtf(r0[0]);                 float i0 = 1.f / l00;
        float l10 = r1[0]*i0, l20 = r2[0]*i0, l30 = r3[0]*i0, l40 = r4[0]*i0, l50 = r5[0]*i0;
        float l11 = sqrtf(r1[1] - l10*l10);       float i1 = 1.f / l11;
        float l21 = (r2[1] - l20*l10)*i1;
        float l31 = (r3[1] - l30*l10)*i1;
        float l41 = (r4[1] - l40*l10)*i1;
        float l51 = (r5[1] - l50*l10)*i1;
        float l22 = sqrtf(r2[2] - l20*l20 - l21*l21); float i2 = 1.f / l22;
        float l32 = (r3[2] - l30*l20 - l31*l21)*i2;
        float l42 = (r4[2] - l40*l20 - l41*l21)*i2;
        float l52 = (r5[2] - l50*l20 - l51*l21)*i2;
        float l33 = sqrtf(r3[3] - l30*l30 - l31*l31 - l32*l32); float i3 = 1.f / l33;
        float l43 = (r4[3] - l40*l30 - l41*l31 - l42*l32)*i3;
        float l53 = (r5[3] - l50*l30 - l51*l31 - l52*l32)*i3;
        float l44 = sqrtf(r4[4] - l40*l40 - l41*l41 - l42*l42 - l43*l43); float i4 = 1.f / l44;
        float l54 = (r5[4] - l50*l40 - l51*l41 - l52*l42 - l53*l43)*i4;
        float l55 = sqrtf(r5[5] - l50*l50 - l51*l51 - l52*l52 - l53*l53 - l54*l54);
        float i5 = 1.f / l55;

        // solve S x = ppct; kk = K row rc
        float y0 =  ppct[0]*i0;
        float y1 = (ppct[1] - l10*y0)*i1;
        float y2 = (ppct[2] - l20*y0 - l21*y1)*i2;
        float y3 = (ppct[3] - l30*y0 - l31*y1 - l32*y2)*i3;
        float y4 = (ppct[4] - l40*y0 - l41*y1 - l42*y2 - l43*y3)*i4;
        float y5 = (ppct[5] - l50*y0 - l51*y1 - l52*y2 - l53*y3 - l54*y4)*i5;
        kk[5] =  y5*i5;
        kk[4] = (y4 - l54*kk[5])*i4;
        kk[3] = (y3 - l43*kk[4] - l53*kk[5])*i3;
        kk[2] = (y2 - l32*kk[3] - l42*kk[4] - l52*kk[5])*i2;
        kk[1] = (y1 - l21*kk[2] - l31*kk[3] - l41*kk[4] - l51*kk[5])*i1;
        kk[0] = (y0 - l10*kk[1] - l20*kk[2] - l30*kk[3] - l40*kk[4] - l50*kk[5])*i0;
    }
    FENCE();
    if (h == 0 && r < 15) wrow6(L + OFF_M2 + r * 20 + 8, kk);  // K -> M2 cols 8-13
    FENCE();
    {   // xp += K e  (ev staged in OFF_VX)
        float e6[6]; rd6(L + OFF_VX, e6);
        xp += kk[0]*e6[0] + kk[1]*e6[1] + kk[2]*e6[2]
            + kk[3]*e6[3] + kk[4]*e6[4] + kk[5]*e6[5];
    }
    SB();

    // ===== phase 4: T3 = Pp - K*PpCt^T; Pn = T3 + (K*R - T3*C^T)*K^T ======
    float pn8[8];
    {
        float t38[8];
        #define T3J(j) do { float pr[6]; rd6(L + OFF_M2 + min(j0 + (j), 14)*20, pr); \
            t38[(j)] = pp8[(j)] - (kk[0]*pr[0]+kk[1]*pr[1]+kk[2]*pr[2] \
                                  +kk[3]*pr[3]+kk[4]*pr[4]+kk[5]*pr[5]); } while(0)
        T3J(0); T3J(1); T3J(2); T3J(3); SB();
        T3J(4); T3J(5); T3J(6); T3J(7); SB();
        if (j0 + 7 >= 15) t38[7] = 0.f;

        float w[6];
        #define GJ(c) w[(c)] = dot8(L + OFF_C + (c)*16 + j0, t38)
        GJ(0); GJ(1); GJ(2); SB(); GJ(3); GJ(4); GJ(5); SB();
        #pragma unroll
        for (int c = 0; c < 6; ++c) w[c] = -(w[c] + XOR16(w[c]));

        #define KRK(k) do { float rk[6]; rd6(L + OFF_R + (k)*8, rk); \
            w[0]+=kk[(k)]*rk[0]; w[1]+=kk[(k)]*rk[1]; w[2]+=kk[(k)]*rk[2]; \
            w[3]+=kk[(k)]*rk[3]; w[4]+=kk[(k)]*rk[4]; w[5]+=kk[(k)]*rk[5]; } while(0)
        KRK(0); KRK(1); KRK(2); SB(); KRK(3); KRK(4); KRK(5); SB();

        #define PNJ(j) do { float krow[6]; rd6(L + OFF_M2 + min(j0 + (j), 14)*20 + 8, krow); \
            pn8[(j)] = t38[(j)] + (w[0]*krow[0]+w[1]*krow[1]+w[2]*krow[2] \
                                  +w[3]*krow[3]+w[4]*krow[4]+w[5]*krow[5]); } while(0)
        PNJ(0); PNJ(1); PNJ(2); PNJ(3); SB();
        PNJ(4); PNJ(5); PNJ(6); PNJ(7); SB();
        if (j0 + 7 >= 15) pn8[7] = 0.f;
    }

    // ---- stage results: Pn -> M1, xp -> S4 dword 6 ----
    FENCE();
    if (r < 15) {
        wrow8(L + OFF_M1 + rc * 20 + j0, pn8);
        if (h == 0) L[OFF_S4 + r * 8 + 6] = xp;
    }
    FENCE(); SB();

    // ---- coalesced stores (unrolled) ----
    {
        float* gpn = o_Pn + (size_t)ib0 * 225;
        float sP[8];
        #pragma unroll
        for (int t = 0; t < 8; ++t) {
            int i = min(tid + t * 64, 449);
            int it = i / 225, idx = i - it * 225;
            int rw = idx / 15, j = idx - rw * 15;
            sP[t] = lds[it * STR + OFF_M1 + rw * 20 + j];
        }
        #pragma unroll
        for (int t = 0; t < 8; ++t) {
            int i = tid + t * 64;
            if (i < limPA) gpn[i] = sP[t];
        }
        float* gxp = o_xp + (size_t)ib0 * 15;
        if (tid < limS) {
            int it = tid / 15, rw = tid - it * 15;
            gxp[tid] = lds[it * STR + OFF_S4 + rw * 8 + 6];
        }
    }
}

extern "C" void kernel_launch(void* const* d_in, const int* in_sizes, int n_in,
                              void* d_out, int out_size, void* d_ws, size_t ws_size,
                              hipStream_t stream) {
    const float* g_state = (const float*)d_in[0];
    const float* g_obs   = (const float*)d_in[1];
    const float* g_u     = (const float*)d_in[2];
    const float* g_P     = (const float*)d_in[3];
    const float* g_A     = (const float*)d_in[4];
    const float* g_B     = (const float*)d_in[5];
    const float* g_C     = (const float*)d_in[6];
    const float* g_D     = (const float*)d_in[7];
    const float* g_c1    = (const float*)d_in[8];
    const float* g_c2    = (const float*)d_in[9];
    const float* g_Q     = (const float*)d_in[10];
    const float* g_R     = (const float*)d_in[11];

    const int bn = in_sizes[0] / 15;
    float* o_xp = (float*)d_out;
    float* o_pn = o_xp + (size_t)bn * 15;

    const int blocks = (bn + 1) / 2;   // 2 items per 64-thread (1-wave) block
    ekf_kernel<<<blocks, 64, 0, stream>>>(
        g_state, g_obs, g_u, g_P, g_A, g_B, g_C, g_D, g_c1, g_c2, g_Q, g_R,
        o_xp, o_pn, bn);
}

// Round 17
// 108.498 us; speedup vs baseline: 1.0235x; 1.0186x over previous
//
#include <hip/hip_runtime.h>

#define XOR16(v)     __shfl_xor((v), 16, 64)
#define FENCE() asm volatile("" ::: "memory")
#define SB() __builtin_amdgcn_sched_barrier(0)

// per-item LDS layout (dwords). 2 items per 64-thread (1-wave) block;
// 32 lanes/item for the fp32 phases: lane (r,h) owns cols [8h..8h+7] of row r.
// Phase 2 (Pp = G H G^T) runs as 3 MFMAs/item using all 64 lanes:
//   Z = H G^T  (H symmetric -> A-frag = H rows; B-frag = G rows)
//   W = Z^T stored bf16 (convert-before-store; D col-segments become W rows)
//   Pp = G Z   (A-frag = G rows; B-frag = W rows, contiguous b128)
#define STR    1932
#define OFF_M1    0    // Pp -> Pn (16 rows x 20) = 320
#define OFF_M2  320    // A fp32 (15x20); after ph1: PpCt cols0-5 / K cols8-13 per row
#define OFF_C   620    // C (6x16, col15 = 0)
#define OFF_S4  716    // B fp32 (15x8; dword6 = xp stage)
#define OFF_R   836    // R (6x8)
#define OFF_VX  884    // x vector -> ev (16)
#define OFF_VU  900    // u vector (8)
#define OFF_GB  908    // Gbf = [A|0|B|0] 16x40 bf16 (320 dw)
#define OFF_HB  1228   // Hbf = blockdiag(P,Q) 32x40 bf16 (640 dw); W bf16 16x40 overlays rows 0..15
#define OFF_SS  1868   // S (6x8) = 48

using bf16x8 = __attribute__((ext_vector_type(8))) short;
using f32x4  = __attribute__((ext_vector_type(4))) float;

__device__ __forceinline__ unsigned short f2bf(float f) {
    union { float f; unsigned u; } v; v.f = f;
    unsigned r = v.u + 0x7FFFu + ((v.u >> 16) & 1u);   // RNE
    return (unsigned short)(r >> 16);
}
__device__ __forceinline__ float dot8(const float* Lr, const float* v) {
    float4 x0 = *(const float4*)(Lr);
    float4 x1 = *(const float4*)(Lr + 4);
    return v[0]*x0.x + v[1]*x0.y + v[2]*x0.z + v[3]*x0.w
         + v[4]*x1.x + v[5]*x1.y + v[6]*x1.z + v[7]*x1.w;
}
__device__ __forceinline__ void rd8(const float* Lr, float* v) {
    float4 x0 = *(const float4*)(Lr);
    float4 x1 = *(const float4*)(Lr + 4);
    v[0]=x0.x; v[1]=x0.y; v[2]=x0.z; v[3]=x0.w;
    v[4]=x1.x; v[5]=x1.y; v[6]=x1.z; v[7]=x1.w;
}
__device__ __forceinline__ float dot6(const float* Lr, const float* v) {
    float4 x0 = *(const float4*)(Lr);
    float2 x1 = *(const float2*)(Lr + 4);
    return v[0]*x0.x + v[1]*x0.y + v[2]*x0.z + v[3]*x0.w + v[4]*x1.x + v[5]*x1.y;
}
__device__ __forceinline__ void rd6(const float* Lr, float* v) {
    float4 x0 = *(const float4*)(Lr);
    float2 x1 = *(const float2*)(Lr + 4);
    v[0]=x0.x; v[1]=x0.y; v[2]=x0.z; v[3]=x0.w; v[4]=x1.x; v[5]=x1.y;
}
__device__ __forceinline__ void wrow6(float* Lr, const float* v) {
    *(float4*)(Lr)     = make_float4(v[0],v[1],v[2],v[3]);
    *(float2*)(Lr + 4) = make_float2(v[4],v[5]);
}
__device__ __forceinline__ void wrow8(float* Lr, const float* v) {
    *(float4*)(Lr)     = make_float4(v[0],v[1],v[2],v[3]);
    *(float4*)(Lr + 4) = make_float4(v[4],v[5],v[6],v[7]);
}

__global__
__attribute__((amdgpu_flat_work_group_size(64, 64)))
__attribute__((amdgpu_waves_per_eu(2, 4)))
void ekf_kernel(
    const float* __restrict__ g_state, const float* __restrict__ g_obs,
    const float* __restrict__ g_u,     const float* __restrict__ g_P,
    const float* __restrict__ g_A,     const float* __restrict__ g_B,
    const float* __restrict__ g_C,     const float* __restrict__ g_D,
    const float* __restrict__ g_c1,    const float* __restrict__ g_c2,
    const float* __restrict__ g_Q,     const float* __restrict__ g_R,
    float* __restrict__ o_xp, float* __restrict__ o_Pn, int bn)
{
    __shared__ __align__(16) float lds[2 * STR];
    const int tid = threadIdx.x;        // 64 threads = ONE wave = 2 items
    const int ib0 = blockIdx.x * 2;
    const int nIt = min(2, bn - ib0);

    const int g   = tid >> 5;           // item within block
    const int s   = tid & 31;           // lane within item
    const int r   = s & 15;             // row
    const int h   = s >> 4;             // column half
    const int j0  = 8 * h;
    const int itc = ib0 + ((g < nIt) ? g : (nIt - 1));
    const int rc  = r < 15 ? r : 14;
    const int rc6 = r < 6 ? r : 5;
    float* L = lds + g * STR;

    // ================= staging: ALL global loads issued up-front ==========
    const float* gp = g_P + (size_t)ib0 * 225;
    const float* ga = g_A + (size_t)ib0 * 225;
    const float* gc = g_C + (size_t)ib0 * 90;
    const float* gb = g_B + (size_t)ib0 * 90;
    const float* gq = g_Q + (size_t)ib0 * 36;
    const float* gr = g_R + (size_t)ib0 * 36;
    const float* gs = g_state + (size_t)ib0 * 15;
    const float* gu = g_u + (size_t)ib0 * 6;
    const int limPA = nIt * 225, limCB = nIt * 90, limQR = nIt * 36;
    const int limS = nIt * 15, limU = nIt * 6;

    float vP[8], vA[8], vC[3], vB[3], vQ[2], vR[2], vS, vU;
    #pragma unroll
    for (int t = 0; t < 8; ++t) {
        int i = min(tid + t * 64, limPA - 1);
        vP[t] = gp[i]; vA[t] = ga[i];
    }
    #pragma unroll
    for (int t = 0; t < 3; ++t) {
        int i = min(tid + t * 64, limCB - 1);
        vC[t] = gc[i]; vB[t] = gb[i];
    }
    #pragma unroll
    for (int t = 0; t < 2; ++t) {
        int i = min(tid + t * 64, limQR - 1);
        vQ[t] = gq[i]; vR[t] = gr[i];
    }
    vS = gs[min(tid, limS - 1)];
    vU = gu[min(tid, limU - 1)];
    float c1v  = g_c1[(size_t)itc * 15 + rc];
    float obsv = g_obs[(size_t)itc * 6 + rc6];
    float c2v  = g_c2[(size_t)itc * 6 + rc6];
    const float* Db = g_D + (size_t)itc * 36 + rc6 * 6;
    float dd0 = Db[0], dd1 = Db[1], dd2 = Db[2], dd3 = Db[3], dd4 = Db[4], dd5 = Db[5];

    // ---- zero Gbf/Hbf (+pad) region [OFF_GB, STR) per item ----
    #pragma unroll
    for (int g2 = 0; g2 < 2; ++g2) {
        #pragma unroll
        for (int t = 0; t < 4; ++t)
            *(float4*)(lds + g2 * STR + OFF_GB + t * 256 + tid * 4)
                = make_float4(0.f, 0.f, 0.f, 0.f);
    }
    FENCE();   // order zero-stores before the b16 data stores

    // ---- fp32 LDS writes ----
    #pragma unroll
    for (int t = 0; t < 8; ++t) {
        int i = tid + t * 64;
        if (i < 450) {
            int it = i / 225, idx = i - it * 225;
            int rw = idx / 15, j = idx - rw * 15;
            lds[it * STR + OFF_M2 + rw * 20 + j] = vA[t];
        }
    }
    #pragma unroll
    for (int t = 0; t < 3; ++t) {
        int i = tid + t * 64;
        if (i < 180) {
            int it = i / 90, idx = i - it * 90;
            int rw = idx / 15, j = idx - rw * 15;
            lds[it * STR + OFF_C + rw * 16 + j] = vC[t];
            int rb = idx / 6, jb = idx - rb * 6;
            lds[it * STR + OFF_S4 + rb * 8 + jb] = vB[t];
        }
    }
    #pragma unroll
    for (int t = 0; t < 2; ++t) {
        int i = tid + t * 64;
        if (i < 72) {
            int it = i / 36, idx = i - it * 36;
            int rw = idx / 6, j = idx - rw * 6;
            lds[it * STR + OFF_R + rw * 8 + j] = vR[t];
        }
    }
    if (tid < 30) { int it = tid / 15, rw = tid - it * 15; lds[it * STR + OFF_VX + rw] = vS; }
    if (tid < 12) { int it = tid / 6,  rw = tid - it * 6;  lds[it * STR + OFF_VU + rw] = vU; }
    if (s < 6)  L[OFF_C + s * 16 + 15] = 0.f;      // C col-15 pad
    if (s == 15) L[OFF_VX + 15] = 0.f;             // x pad

    // ---- bf16 writes: G = [A | 0 | B | 0], H = blockdiag(P, Q) ----
    {
        unsigned short* lb = (unsigned short*)lds;
        #pragma unroll
        for (int t = 0; t < 8; ++t) {
            int i = tid + t * 64;
            if (i < 450) {
                int it = i / 225, idx = i - it * 225;
                int rw = idx / 15, j = idx - rw * 15;
                lb[(it * STR + OFF_GB) * 2 + rw * 40 + j] = f2bf(vA[t]);
                lb[(it * STR + OFF_HB) * 2 + rw * 40 + j] = f2bf(vP[t]);
            }
        }
        #pragma unroll
        for (int t = 0; t < 3; ++t) {
            int i = tid + t * 64;
            if (i < 180) {
                int it = i / 90, idx = i - it * 90;
                int rb = idx / 6, jb = idx - rb * 6;
                lb[(it * STR + OFF_GB) * 2 + rb * 40 + 16 + jb] = f2bf(vB[t]);
            }
        }
        #pragma unroll
        for (int t = 0; t < 2; ++t) {
            int i = tid + t * 64;
            if (i < 72) {
                int it = i / 36, idx = i - it * 36;
                int rq = idx / 6, cq = idx - rq * 6;
                lb[(it * STR + OFF_HB) * 2 + (16 + rq) * 40 + 16 + cq] = f2bf(vQ[t]);
            }
        }
    }
    FENCE(); SB();

    // ================= phase 1: xp0, ev (half-dots + xor-sum) =============
    float xp;
    {
        float xh[8]; rd8(L + OFF_VX + j0, xh);
        float u6[6]; rd6(L + OFF_VU, u6);
        float xpp =  dot8(L + OFF_M2 + rc * 20 + j0, xh);
        float evp = -dot8(L + OFF_C + rc6 * 16 + j0, xh);
        if (h == 0) {
            xpp += c1v + dot6(L + OFF_S4 + rc * 8, u6);
            evp += obsv - c2v
                 - (dd0*u6[0] + dd1*u6[1] + dd2*u6[2]
                  + dd3*u6[3] + dd4*u6[4] + dd5*u6[5]);
        }
        xp = xpp + XOR16(xpp);
        float ev = evp + XOR16(evp);
        FENCE();
        if (h == 0 && r < 6) L[OFF_VX + r] = ev;   // stage ev (x dead)
        FENCE();
    }

    // ============ phase 2: Pp = G H G^T via MFMA (bf16, fp32 acc) =========
    const int q  = tid >> 4;          // k-group / D-row group (0..3)
    const int cL = tid & 15;          // row / col index within fragment
    {
        char* lb = (char*)lds;
        bf16x8 ga0 = *(bf16x8*)(lb + (0*STR + OFF_GB)*4 + cL*80 + q*16);
        bf16x8 ga1 = *(bf16x8*)(lb + (1*STR + OFF_GB)*4 + cL*80 + q*16);
        bf16x8 ht0 = *(bf16x8*)(lb + (0*STR + OFF_HB)*4 + cL*80 + q*16);
        bf16x8 hb0 = *(bf16x8*)(lb + (0*STR + OFF_HB)*4 + (16+cL)*80 + q*16);
        bf16x8 ht1 = *(bf16x8*)(lb + (1*STR + OFF_HB)*4 + cL*80 + q*16);
        bf16x8 hb1 = *(bf16x8*)(lb + (1*STR + OFF_HB)*4 + (16+cL)*80 + q*16);
        f32x4 z = {0.f, 0.f, 0.f, 0.f};
        f32x4 zt0 = __builtin_amdgcn_mfma_f32_16x16x32_bf16(ht0, ga0, z, 0, 0, 0);
        f32x4 zb0 = __builtin_amdgcn_mfma_f32_16x16x32_bf16(hb0, ga0, z, 0, 0, 0);
        f32x4 zt1 = __builtin_amdgcn_mfma_f32_16x16x32_bf16(ht1, ga1, z, 0, 0, 0);
        f32x4 zb1 = __builtin_amdgcn_mfma_f32_16x16x32_bf16(hb1, ga1, z, 0, 0, 0);
        FENCE();
        {
            unsigned t0 = (unsigned)f2bf(zt0[0]) | ((unsigned)f2bf(zt0[1]) << 16);
            unsigned t1 = (unsigned)f2bf(zt0[2]) | ((unsigned)f2bf(zt0[3]) << 16);
            unsigned b0 = (unsigned)f2bf(zb0[0]) | ((unsigned)f2bf(zb0[1]) << 16);
            unsigned b1 = (unsigned)f2bf(zb0[2]) | ((unsigned)f2bf(zb0[3]) << 16);
            *(uint2*)(lb + (0*STR + OFF_HB)*4 + cL*80 + 8*q)      = make_uint2(t0, t1);
            *(uint2*)(lb + (0*STR + OFF_HB)*4 + cL*80 + 32 + 8*q) = make_uint2(b0, b1);
            unsigned u0 = (unsigned)f2bf(zt1[0]) | ((unsigned)f2bf(zt1[1]) << 16);
            unsigned u1 = (unsigned)f2bf(zt1[2]) | ((unsigned)f2bf(zt1[3]) << 16);
            unsigned v0 = (unsigned)f2bf(zb1[0]) | ((unsigned)f2bf(zb1[1]) << 16);
            unsigned v1 = (unsigned)f2bf(zb1[2]) | ((unsigned)f2bf(zb1[3]) << 16);
            *(uint2*)(lb + (1*STR + OFF_HB)*4 + cL*80 + 8*q)      = make_uint2(u0, u1);
            *(uint2*)(lb + (1*STR + OFF_HB)*4 + cL*80 + 32 + 8*q) = make_uint2(v0, v1);
        }
        FENCE(); SB();
        bf16x8 w0 = *(bf16x8*)(lb + (0*STR + OFF_HB)*4 + cL*80 + 16*q);
        bf16x8 w1 = *(bf16x8*)(lb + (1*STR + OFF_HB)*4 + cL*80 + 16*q);
        f32x4 pp0 = __builtin_amdgcn_mfma_f32_16x16x32_bf16(ga0, w0, z, 0, 0, 0);
        f32x4 pp1 = __builtin_amdgcn_mfma_f32_16x16x32_bf16(ga1, w1, z, 0, 0, 0);
        FENCE();
        *(f32x4*)(lds + 0*STR + OFF_M1 + cL*20 + 4*q) = pp0;
        *(f32x4*)(lds + 1*STR + OFF_M1 + cL*20 + 4*q) = pp1;
        FENCE(); SB();
    }

    // ================= phase 3: K (Cholesky in registers) =================
    float pp8[8];
    rd8(L + OFF_M1 + rc * 20 + j0, pp8);   // my Pp row half
    float ppct[6];
    {
        #define PCJ(c) ppct[(c)] = dot8(L + OFF_C + (c)*16 + j0, pp8)
        PCJ(0); PCJ(1); PCJ(2); PCJ(3); PCJ(4); PCJ(5);
        #pragma unroll
        for (int c = 0; c < 6; ++c) ppct[c] += XOR16(ppct[c]);
    }
    FENCE();
    if (h == 0 && r < 15) wrow6(L + OFF_M2 + r * 20, ppct);  // PpCt -> M2 cols 0-5 (A dead)
    FENCE();

    float kk[6];
    {
        float sm[6];
        #pragma unroll
        for (int c = 0; c < 6; ++c) sm[c] = 0.f;
        {
            float ch[8]; rd8(L + OFF_C + rc6 * 16 + j0, ch);
            #define SAK(k) do { float pr[6]; rd6(L + OFF_M2 + min(j0 + (k), 14)*20, pr); \
                float cv = ch[(k)]; \
                sm[0]+=cv*pr[0]; sm[1]+=cv*pr[1]; sm[2]+=cv*pr[2]; \
                sm[3]+=cv*pr[3]; sm[4]+=cv*pr[4]; sm[5]+=cv*pr[5]; } while(0)
            SAK(0); SAK(1); SAK(2); SAK(3);
            SAK(4); SAK(5); SAK(6); SAK(7);
        }
        #pragma unroll
        for (int c = 0; c < 6; ++c) sm[c] += XOR16(sm[c]);
        if (h == 0 && r < 6) {
            float rr6[6]; rd6(L + OFF_R + r * 8, rr6);
            float srow[6];
            #pragma unroll
            for (int c = 0; c < 6; ++c) srow[c] = sm[c] + rr6[c];
            wrow6(L + OFF_SS + r * 8, srow);                // S -> SS
        }
        FENCE();

        float r0[6], r1[6], r2[6], r3[6], r4[6], r5[6];
        rd6(L + OFF_SS + 0*8, r0); rd6(L + OFF_SS + 1*8, r1); rd6(L + OFF_SS + 2*8, r2);
        rd6(L + OFF_SS + 3*8, r3); rd6(L + OFF_SS + 4*8, r4); rd6(L + OFF_SS + 5*8, r5);

        // Cholesky S = L L^T (registers only; S SPD, diag >= 0.1)
        float l00 = sqrtf(r0[0]);                 float i0 = 1.f / l00;
        float l10 = r1[0]*i0, l20 = r2[0]*i0, l30 = r3[0]*i0, l40 = r4[0]*i0, l50 = r5[0]*i0;
        float l11 = sqrtf(r1[1] - l10*l10);       float i1 = 1.f / l11;
        float l21 = (r2[1] - l20*l10)*i1;
        float l31 = (r3[1] - l30*l10)*i1;
        float l41 = (r4[1] - l40*l10)*i1;
        float l51 = (r5[1] - l50*l10)*i1;
        float l22 = sqrtf(r2[2] - l20*l20 - l21*l21); float i2 = 1.f / l22;
        float l32 = (r3[2] - l30*l20 - l31*l21)*i2;
        float l42 = (r4[2] - l40*l20 - l41*l21)*i2;
        float l52 = (r5[2] - l50*l20 - l51*l21)*i2;
        float l33 = sqrtf(r3[3] - l30*l30 - l31*l31 - l32*l32); float i3 = 1.f / l33;
        float l43 = (r4[3] - l40*l30 - l41*l31 - l42*l32)*i3;
        float l53 = (r5[3] - l50*l30 - l51*l31 - l52*l32)*i3;
        float l44 = sqrtf(r4[4] - l40*l40 - l41*l41 - l42*l42 - l43*l43); float i4 = 1.f / l44;
        float l54 = (r5[4] - l50*l40 - l51*l41 - l52*l42 - l53*l43)*i4;
        float l55 = sqrtf(r5[5] - l50*l50 - l51*l51 - l52*l52 - l53*l53 - l54*l54);
        float i5 = 1.f / l55;

        float y0 =  ppct[0]*i0;
        float y1 = (ppct[1] - l10*y0)*i1;
        float y2 = (ppct[2] - l20*y0 - l21*y1)*i2;
        float y3 = (ppct[3] - l30*y0 - l31*y1 - l32*y2)*i3;
        float y4 = (ppct[4] - l40*y0 - l41*y1 - l42*y2 - l43*y3)*i4;
        float y5 = (ppct[5] - l50*y0 - l51*y1 - l52*y2 - l53*y3 - l54*y4)*i5;
        kk[5] =  y5*i5;
        kk[4] = (y4 - l54*kk[5])*i4;
        kk[3] = (y3 - l43*kk[4] - l53*kk[5])*i3;
        kk[2] = (y2 - l32*kk[3] - l42*kk[4] - l52*kk[5])*i2;
        kk[1] = (y1 - l21*kk[2] - l31*kk[3] - l41*kk[4] - l51*kk[5])*i1;
        kk[0] = (y0 - l10*kk[1] - l20*kk[2] - l30*kk[3] - l40*kk[4] - l50*kk[5])*i0;
    }
    FENCE();
    if (h == 0 && r < 15) wrow6(L + OFF_M2 + r * 20 + 8, kk);  // K -> M2 cols 8-13
    FENCE();
    {   // xp += K e  (ev staged in OFF_VX)
        float e6[6]; rd6(L + OFF_VX, e6);
        xp += kk[0]*e6[0] + kk[1]*e6[1] + kk[2]*e6[2]
            + kk[3]*e6[3] + kk[4]*e6[4] + kk[5]*e6[5];
    }

    // ===== phase 4: T3 = Pp - K*PpCt^T; Pn = T3 + (K*R - T3*C^T)*K^T ======
    float pn8[8];
    {
        float t38[8];
        #define T3J(j) do { float pr[6]; rd6(L + OFF_M2 + min(j0 + (j), 14)*20, pr); \
            t38[(j)] = pp8[(j)] - (kk[0]*pr[0]+kk[1]*pr[1]+kk[2]*pr[2] \
                                  +kk[3]*pr[3]+kk[4]*pr[4]+kk[5]*pr[5]); } while(0)
        T3J(0); T3J(1); T3J(2); T3J(3);
        T3J(4); T3J(5); T3J(6); T3J(7);
        if (j0 + 7 >= 15) t38[7] = 0.f;

        float w[6];
        #define GJ(c) w[(c)] = dot8(L + OFF_C + (c)*16 + j0, t38)
        GJ(0); GJ(1); GJ(2); GJ(3); GJ(4); GJ(5);
        #pragma unroll
        for (int c = 0; c < 6; ++c) w[c] = -(w[c] + XOR16(w[c]));

        #define KRK(k) do { float rk[6]; rd6(L + OFF_R + (k)*8, rk); \
            w[0]+=kk[(k)]*rk[0]; w[1]+=kk[(k)]*rk[1]; w[2]+=kk[(k)]*rk[2]; \
            w[3]+=kk[(k)]*rk[3]; w[4]+=kk[(k)]*rk[4]; w[5]+=kk[(k)]*rk[5]; } while(0)
        KRK(0); KRK(1); KRK(2); KRK(3); KRK(4); KRK(5);

        #define PNJ(j) do { float krow[6]; rd6(L + OFF_M2 + min(j0 + (j), 14)*20 + 8, krow); \
            pn8[(j)] = t38[(j)] + (w[0]*krow[0]+w[1]*krow[1]+w[2]*krow[2] \
                                  +w[3]*krow[3]+w[4]*krow[4]+w[5]*krow[5]); } while(0)
        PNJ(0); PNJ(1); PNJ(2); PNJ(3);
        PNJ(4); PNJ(5); PNJ(6); PNJ(7);
        if (j0 + 7 >= 15) pn8[7] = 0.f;
    }

    // ---- stage results: Pn -> M1, xp -> S4 dword 6 ----
    FENCE();
    if (r < 15) {
        wrow8(L + OFF_M1 + rc * 20 + j0, pn8);
        if (h == 0) L[OFF_S4 + r * 8 + 6] = xp;
    }
    FENCE();

    // ---- coalesced stores (unrolled: LDS reads pipelined, then stores) ----
    {
        float* gpn = o_Pn + (size_t)ib0 * 225;
        float sP[8];
        #pragma unroll
        for (int t = 0; t < 8; ++t) {
            int i = min(tid + t * 64, 449);
            int it = i / 225, idx = i - it * 225;
            int rw = idx / 15, j = idx - rw * 15;
            sP[t] = lds[it * STR + OFF_M1 + rw * 20 + j];
        }
        #pragma unroll
        for (int t = 0; t < 8; ++t) {
            int i = tid + t * 64;
            if (i < limPA) gpn[i] = sP[t];
        }
        float* gxp = o_xp + (size_t)ib0 * 15;
        if (tid < limS) {
            int it = tid / 15, rw = tid - it * 15;
            gxp[tid] = lds[it * STR + OFF_S4 + rw * 8 + 6];
        }
    }
}

extern "C" void kernel_launch(void* const* d_in, const int* in_sizes, int n_in,
                              void* d_out, int out_size, void* d_ws, size_t ws_size,
                              hipStream_t stream) {
    const float* g_state = (const float*)d_in[0];
    const float* g_obs   = (const float*)d_in[1];
    const float* g_u     = (const float*)d_in[2];
    const float* g_P     = (const float*)d_in[3];
    const float* g_A     = (const float*)d_in[4];
    const float* g_B     = (const float*)d_in[5];
    const float* g_C     = (const float*)d_in[6];
    const float* g_D     = (const float*)d_in[7];
    const float* g_c1    = (const float*)d_in[8];
    const float* g_c2    = (const float*)d_in[9];
    const float* g_Q     = (const float*)d_in[10];
    const float* g_R     = (const float*)d_in[11];

    const int bn = in_sizes[0] / 15;
    float* o_xp = (float*)d_out;
    float* o_pn = o_xp + (size_t)bn * 15;

    const int blocks = (bn + 1) / 2;   // 2 items per 64-thread (1-wave) block
    ekf_kernel<<<blocks, 64, 0, stream>>>(
        g_state, g_obs, g_u, g_P, g_A, g_B, g_C, g_D, g_c1, g_c2, g_Q, g_R,
        o_xp, o_pn, bn);
}

// Round 18
// 100.679 us; speedup vs baseline: 1.1030x; 1.0777x over previous
//
#include <hip/hip_runtime.h>

#define XOR16(v)     __shfl_xor((v), 16, 64)
#define FENCE() asm volatile("" ::: "memory")
#define SB() __builtin_amdgcn_sched_barrier(0)

// per-item LDS layout (dwords). 2 items per 64-thread (1-wave) block;
// 32 lanes/item fp32 phases: lane (r,h) owns cols [8h..8h+7] of row r.
// Small matrices (PpCt/K/S/R/C) are bf16-packed: one b128 per 6-8 value row.
#define STR    1544
#define OFF_M1    0    // Pp -> Pn fp32 (16 x 20)
#define OFF_PK  320    // PpCt bf16 rows (15 x 4dw; dw3 = xp fp32 stage)
#define OFF_KB  380    // K bf16 rows (15 x 4dw)
#define OFF_SB  440    // S bf16 rows (6 x 4dw)
#define OFF_RB  464    // R bf16 rows (6 x 4dw)
#define OFF_VX  488    // x fp32 (16) -> ev fp32 (6)
#define OFF_VU  504    // u fp32 (8)
#define OFF_CB  520    // C bf16 (6 rows x 8dw = 16 bf16, col15 = 0)  [zero region starts]
#define OFF_GB  568    // G bf16 [A|0|B|0] 16 x 20dw
#define OFF_HB  888    // H bf16 blockdiag(P,Q) 32 x 20dw; W overlay rows 0-15
// zero region: [OFF_CB, OFF_CB + 1024) = [520, 1544)

using bf16x8 = __attribute__((ext_vector_type(8))) short;
using f32x4  = __attribute__((ext_vector_type(4))) float;

__device__ __forceinline__ unsigned short f2bf(float f) {
    union { float f; unsigned u; } v; v.f = f;
    unsigned r = v.u + 0x7FFFu + ((v.u >> 16) & 1u);   // RNE
    return (unsigned short)(r >> 16);
}
__device__ __forceinline__ uint4 ldu4(const float* p) { return *(const uint4*)p; }
__device__ __forceinline__ void unpk8(const uint4 u, float* v) {
    v[0]=__uint_as_float(u.x<<16); v[1]=__uint_as_float(u.x&0xffff0000u);
    v[2]=__uint_as_float(u.y<<16); v[3]=__uint_as_float(u.y&0xffff0000u);
    v[4]=__uint_as_float(u.z<<16); v[5]=__uint_as_float(u.z&0xffff0000u);
    v[6]=__uint_as_float(u.w<<16); v[7]=__uint_as_float(u.w&0xffff0000u);
}
__device__ __forceinline__ void unpk6(const uint4 u, float* v) {
    v[0]=__uint_as_float(u.x<<16); v[1]=__uint_as_float(u.x&0xffff0000u);
    v[2]=__uint_as_float(u.y<<16); v[3]=__uint_as_float(u.y&0xffff0000u);
    v[4]=__uint_as_float(u.z<<16); v[5]=__uint_as_float(u.z&0xffff0000u);
}
__device__ __forceinline__ void wpk6(float* Lr, const float* v) {
    uint4 u;
    u.x = (unsigned)f2bf(v[0]) | ((unsigned)f2bf(v[1])<<16);
    u.y = (unsigned)f2bf(v[2]) | ((unsigned)f2bf(v[3])<<16);
    u.z = (unsigned)f2bf(v[4]) | ((unsigned)f2bf(v[5])<<16);
    u.w = 0;
    *(uint4*)Lr = u;
}
__device__ __forceinline__ void rd8(const float* Lr, float* v) {
    float4 x0 = *(const float4*)(Lr);
    float4 x1 = *(const float4*)(Lr + 4);
    v[0]=x0.x; v[1]=x0.y; v[2]=x0.z; v[3]=x0.w;
    v[4]=x1.x; v[5]=x1.y; v[6]=x1.z; v[7]=x1.w;
}
__device__ __forceinline__ void rd6(const float* Lr, float* v) {
    float4 x0 = *(const float4*)(Lr);
    float2 x1 = *(const float2*)(Lr + 4);
    v[0]=x0.x; v[1]=x0.y; v[2]=x0.z; v[3]=x0.w; v[4]=x1.x; v[5]=x1.y;
}
__device__ __forceinline__ void wrow8(float* Lr, const float* v) {
    *(float4*)(Lr)     = make_float4(v[0],v[1],v[2],v[3]);
    *(float4*)(Lr + 4) = make_float4(v[4],v[5],v[6],v[7]);
}

__global__
__attribute__((amdgpu_flat_work_group_size(64, 64)))
__attribute__((amdgpu_waves_per_eu(2, 4)))
void ekf_kernel(
    const float* __restrict__ g_state, const float* __restrict__ g_obs,
    const float* __restrict__ g_u,     const float* __restrict__ g_P,
    const float* __restrict__ g_A,     const float* __restrict__ g_B,
    const float* __restrict__ g_C,     const float* __restrict__ g_D,
    const float* __restrict__ g_c1,    const float* __restrict__ g_c2,
    const float* __restrict__ g_Q,     const float* __restrict__ g_R,
    float* __restrict__ o_xp, float* __restrict__ o_Pn, int bn)
{
    __shared__ __align__(16) float lds[2 * STR];
    const int tid = threadIdx.x;        // 64 threads = ONE wave = 2 items
    const int ib0 = blockIdx.x * 2;
    const int nIt = min(2, bn - ib0);

    const int g   = tid >> 5;           // item within block
    const int s   = tid & 31;           // lane within item
    const int r   = s & 15;             // row
    const int h   = s >> 4;             // column half
    const int j0  = 8 * h;
    const int itc = ib0 + ((g < nIt) ? g : (nIt - 1));
    const int rc  = r < 15 ? r : 14;
    const int rc6 = r < 6 ? r : 5;
    float* L = lds + g * STR;

    // ================= staging: ALL global loads issued up-front ==========
    const float* gp = g_P + (size_t)ib0 * 225;
    const float* ga = g_A + (size_t)ib0 * 225;
    const float* gc = g_C + (size_t)ib0 * 90;
    const float* gb = g_B + (size_t)ib0 * 90;
    const float* gq = g_Q + (size_t)ib0 * 36;
    const float* gr = g_R + (size_t)ib0 * 36;
    const float* gs = g_state + (size_t)ib0 * 15;
    const float* gu = g_u + (size_t)ib0 * 6;
    const int limPA = nIt * 225, limCB = nIt * 90, limQR = nIt * 36;
    const int limS = nIt * 15, limU = nIt * 6;

    float vP[8], vA[8], vC[3], vB[3], vQ[2], vR[2], vS, vU;
    #pragma unroll
    for (int t = 0; t < 8; ++t) {
        int i = min(tid + t * 64, limPA - 1);
        vP[t] = gp[i]; vA[t] = ga[i];
    }
    #pragma unroll
    for (int t = 0; t < 3; ++t) {
        int i = min(tid + t * 64, limCB - 1);
        vC[t] = gc[i]; vB[t] = gb[i];
    }
    #pragma unroll
    for (int t = 0; t < 2; ++t) {
        int i = min(tid + t * 64, limQR - 1);
        vQ[t] = gq[i]; vR[t] = gr[i];
    }
    vS = gs[min(tid, limS - 1)];
    vU = gu[min(tid, limU - 1)];
    float c1v  = g_c1[(size_t)itc * 15 + rc];
    float obsv = g_obs[(size_t)itc * 6 + rc6];
    float c2v  = g_c2[(size_t)itc * 6 + rc6];
    const float* Db = g_D + (size_t)itc * 36 + rc6 * 6;
    float dd0 = Db[0], dd1 = Db[1], dd2 = Db[2], dd3 = Db[3], dd4 = Db[4], dd5 = Db[5];

    // ---- zero CB/GB/HB (+pads) region [OFF_CB, STR) per item ----
    #pragma unroll
    for (int g2 = 0; g2 < 2; ++g2) {
        #pragma unroll
        for (int t = 0; t < 4; ++t)
            *(float4*)(lds + g2 * STR + OFF_CB + t * 256 + tid * 4)
                = make_float4(0.f, 0.f, 0.f, 0.f);
    }
    FENCE();   // order zero-stores before the bf16 data stores

    // ---- fp32 LDS writes: x, u only ----
    if (tid < 30) { int it = tid / 15, rw = tid - it * 15; lds[it * STR + OFF_VX + rw] = vS; }
    if (tid < 12) { int it = tid / 6,  rw = tid - it * 6;  lds[it * STR + OFF_VU + rw] = vU; }
    if (s == 15) L[OFF_VX + 15] = 0.f;             // x pad

    // ---- bf16 writes: G = [A|0|B|0], H = blockdiag(P,Q), C, R ----
    {
        unsigned short* lb = (unsigned short*)lds;
        #pragma unroll
        for (int t = 0; t < 8; ++t) {
            int i = tid + t * 64;
            if (i < 450) {
                int it = i / 225, idx = i - it * 225;
                int rw = idx / 15, j = idx - rw * 15;
                lb[(it * STR + OFF_GB) * 2 + rw * 40 + j] = f2bf(vA[t]);
                lb[(it * STR + OFF_HB) * 2 + rw * 40 + j] = f2bf(vP[t]);
            }
        }
        #pragma unroll
        for (int t = 0; t < 3; ++t) {
            int i = tid + t * 64;
            if (i < 180) {
                int it = i / 90, idx = i - it * 90;
                int rb = idx / 6, jb = idx - rb * 6;
                lb[(it * STR + OFF_GB) * 2 + rb * 40 + 16 + jb] = f2bf(vB[t]);
                int rw = idx / 15, j = idx - rw * 15;
                lb[(it * STR + OFF_CB) * 2 + rw * 16 + j] = f2bf(vC[t]);
            }
        }
        #pragma unroll
        for (int t = 0; t < 2; ++t) {
            int i = tid + t * 64;
            if (i < 72) {
                int it = i / 36, idx = i - it * 36;
                int rq = idx / 6, cq = idx - rq * 6;
                lb[(it * STR + OFF_HB) * 2 + (16 + rq) * 40 + 16 + cq] = f2bf(vQ[t]);
                lb[(it * STR + OFF_RB) * 2 + rq * 8 + cq] = f2bf(vR[t]);
            }
        }
    }
    FENCE(); SB();

    // ================= phase 1: xp0, ev (bf16 A/B/C rows, fp32 x/u) =======
    float xp;
    {
        float xh[8]; rd8(L + OFF_VX + j0, xh);
        float u6[6]; rd6(L + OFF_VU, u6);
        float ar[8]; unpk8(ldu4(L + OFF_GB + rc * 20 + 4 * h), ar);   // A row half
        float cr[8]; unpk8(ldu4(L + OFF_CB + rc6 * 8 + 4 * h), cr);   // C row half
        float xpp = ar[0]*xh[0]+ar[1]*xh[1]+ar[2]*xh[2]+ar[3]*xh[3]
                  + ar[4]*xh[4]+ar[5]*xh[5]+ar[6]*xh[6]+ar[7]*xh[7];
        float evp = -(cr[0]*xh[0]+cr[1]*xh[1]+cr[2]*xh[2]+cr[3]*xh[3]
                    + cr[4]*xh[4]+cr[5]*xh[5]+cr[6]*xh[6]+cr[7]*xh[7]);
        if (h == 0) {
            float br[6]; unpk6(ldu4(L + OFF_GB + rc * 20 + 8), br);   // B row
            xpp += c1v + br[0]*u6[0]+br[1]*u6[1]+br[2]*u6[2]
                       + br[3]*u6[3]+br[4]*u6[4]+br[5]*u6[5];
            evp += obsv - c2v
                 - (dd0*u6[0] + dd1*u6[1] + dd2*u6[2]
                  + dd3*u6[3] + dd4*u6[4] + dd5*u6[5]);
        }
        xp = xpp + XOR16(xpp);
        float ev = evp + XOR16(evp);
        FENCE();
        if (h == 0 && r < 6) L[OFF_VX + r] = ev;   // stage ev (x dead)
        FENCE();
    }

    // ============ phase 2: Pp = G H G^T via MFMA (bf16, fp32 acc) =========
    const int q  = tid >> 4;          // k-group / D-row group (0..3)
    const int cL = tid & 15;          // row / col index within fragment
    {
        char* lb = (char*)lds;
        bf16x8 ga0 = *(bf16x8*)(lb + (0*STR + OFF_GB)*4 + cL*80 + q*16);
        bf16x8 ga1 = *(bf16x8*)(lb + (1*STR + OFF_GB)*4 + cL*80 + q*16);
        bf16x8 ht0 = *(bf16x8*)(lb + (0*STR + OFF_HB)*4 + cL*80 + q*16);
        bf16x8 hb0 = *(bf16x8*)(lb + (0*STR + OFF_HB)*4 + (16+cL)*80 + q*16);
        bf16x8 ht1 = *(bf16x8*)(lb + (1*STR + OFF_HB)*4 + cL*80 + q*16);
        bf16x8 hb1 = *(bf16x8*)(lb + (1*STR + OFF_HB)*4 + (16+cL)*80 + q*16);
        f32x4 z = {0.f, 0.f, 0.f, 0.f};
        f32x4 zt0 = __builtin_amdgcn_mfma_f32_16x16x32_bf16(ht0, ga0, z, 0, 0, 0);
        f32x4 zb0 = __builtin_amdgcn_mfma_f32_16x16x32_bf16(hb0, ga0, z, 0, 0, 0);
        f32x4 zt1 = __builtin_amdgcn_mfma_f32_16x16x32_bf16(ht1, ga1, z, 0, 0, 0);
        f32x4 zb1 = __builtin_amdgcn_mfma_f32_16x16x32_bf16(hb1, ga1, z, 0, 0, 0);
        FENCE();
        {
            unsigned t0 = (unsigned)f2bf(zt0[0]) | ((unsigned)f2bf(zt0[1]) << 16);
            unsigned t1 = (unsigned)f2bf(zt0[2]) | ((unsigned)f2bf(zt0[3]) << 16);
            unsigned b0 = (unsigned)f2bf(zb0[0]) | ((unsigned)f2bf(zb0[1]) << 16);
            unsigned b1 = (unsigned)f2bf(zb0[2]) | ((unsigned)f2bf(zb0[3]) << 16);
            *(uint2*)(lb + (0*STR + OFF_HB)*4 + cL*80 + 8*q)      = make_uint2(t0, t1);
            *(uint2*)(lb + (0*STR + OFF_HB)*4 + cL*80 + 32 + 8*q) = make_uint2(b0, b1);
            unsigned u0 = (unsigned)f2bf(zt1[0]) | ((unsigned)f2bf(zt1[1]) << 16);
            unsigned u1 = (unsigned)f2bf(zt1[2]) | ((unsigned)f2bf(zt1[3]) << 16);
            unsigned v0 = (unsigned)f2bf(zb1[0]) | ((unsigned)f2bf(zb1[1]) << 16);
            unsigned v1 = (unsigned)f2bf(zb1[2]) | ((unsigned)f2bf(zb1[3]) << 16);
            *(uint2*)(lb + (1*STR + OFF_HB)*4 + cL*80 + 8*q)      = make_uint2(u0, u1);
            *(uint2*)(lb + (1*STR + OFF_HB)*4 + cL*80 + 32 + 8*q) = make_uint2(v0, v1);
        }
        FENCE(); SB();
        bf16x8 w0 = *(bf16x8*)(lb + (0*STR + OFF_HB)*4 + cL*80 + 16*q);
        bf16x8 w1 = *(bf16x8*)(lb + (1*STR + OFF_HB)*4 + cL*80 + 16*q);
        f32x4 pp0 = __builtin_amdgcn_mfma_f32_16x16x32_bf16(ga0, w0, z, 0, 0, 0);
        f32x4 pp1 = __builtin_amdgcn_mfma_f32_16x16x32_bf16(ga1, w1, z, 0, 0, 0);
        FENCE();
        *(f32x4*)(lds + 0*STR + OFF_M1 + cL*20 + 4*q) = pp0;
        *(f32x4*)(lds + 1*STR + OFF_M1 + cL*20 + 4*q) = pp1;
        FENCE(); SB();
    }

    // ================= phase 3: K (Cholesky in registers) =================
    float pp8[8];
    rd8(L + OFF_M1 + rc * 20 + j0, pp8);   // my Pp row half (fp32)
    float ppct[6];
    {
        #define PCJ(c) do { float cc[8]; unpk8(ldu4(L + OFF_CB + (c)*8 + 4*h), cc); \
            ppct[(c)] = cc[0]*pp8[0]+cc[1]*pp8[1]+cc[2]*pp8[2]+cc[3]*pp8[3] \
                      + cc[4]*pp8[4]+cc[5]*pp8[5]+cc[6]*pp8[6]+cc[7]*pp8[7]; } while(0)
        PCJ(0); PCJ(1); PCJ(2); PCJ(3); PCJ(4); PCJ(5);
        #pragma unroll
        for (int c = 0; c < 6; ++c) ppct[c] += XOR16(ppct[c]);
    }
    FENCE();
    if (h == 0 && r < 15) wpk6(L + OFF_PK + 4 * r, ppct);  // PpCt bf16 rows
    FENCE();

    float kk[6];
    {
        float sm[6];
        #pragma unroll
        for (int c = 0; c < 6; ++c) sm[c] = 0.f;
        {
            float ch[8]; unpk8(ldu4(L + OFF_CB + rc6 * 8 + 4 * h), ch);
            #define SAK(k) do { float pr[6]; unpk6(ldu4(L + OFF_PK + 4*min(j0 + (k), 14)), pr); \
                float cv = ch[(k)]; \
                sm[0]+=cv*pr[0]; sm[1]+=cv*pr[1]; sm[2]+=cv*pr[2]; \
                sm[3]+=cv*pr[3]; sm[4]+=cv*pr[4]; sm[5]+=cv*pr[5]; } while(0)
            SAK(0); SAK(1); SAK(2); SAK(3);
            SAK(4); SAK(5); SAK(6); SAK(7);
        }
        #pragma unroll
        for (int c = 0; c < 6; ++c) sm[c] += XOR16(sm[c]);
        if (h == 0 && r < 6) {
            float rr6[6]; unpk6(ldu4(L + OFF_RB + 4 * r), rr6);
            float srow[6];
            #pragma unroll
            for (int c = 0; c < 6; ++c) srow[c] = sm[c] + rr6[c];
            wpk6(L + OFF_SB + 4 * r, srow);                 // S bf16 rows
        }
        FENCE();

        float r0[6], r1[6], r2[6], r3[6], r4[6], r5[6];
        unpk6(ldu4(L + OFF_SB + 0),  r0); unpk6(ldu4(L + OFF_SB + 4),  r1);
        unpk6(ldu4(L + OFF_SB + 8),  r2); unpk6(ldu4(L + OFF_SB + 12), r3);
        unpk6(ldu4(L + OFF_SB + 16), r4); unpk6(ldu4(L + OFF_SB + 20), r5);

        // Cholesky S = L L^T (registers only; S SPD, diag >= 0.1)
        float l00 = sqrtf(r0[0]);                 float i0 = 1.f / l00;
        float l10 = r1[0]*i0, l20 = r2[0]*i0, l30 = r3[0]*i0, l40 = r4[0]*i0, l50 = r5[0]*i0;
        float l11 = sqrtf(r1[1] - l10*l10);       float i1 = 1.f / l11;
        float l21 = (r2[1] - l20*l10)*i1;
        float l31 = (r3[1] - l30*l10)*i1;
        float l41 = (r4[1] - l40*l10)*i1;
        float l51 = (r5[1] - l50*l10)*i1;
        float l22 = sqrtf(r2[2] - l20*l20 - l21*l21); float i2 = 1.f / l22;
        float l32 = (r3[2] - l30*l20 - l31*l21)*i2;
        float l42 = (r4[2] - l40*l20 - l41*l21)*i2;
        float l52 = (r5[2] - l50*l20 - l51*l21)*i2;
        float l33 = sqrtf(r3[3] - l30*l30 - l31*l31 - l32*l32); float i3 = 1.f / l33;
        float l43 = (r4[3] - l40*l30 - l41*l31 - l42*l32)*i3;
        float l53 = (r5[3] - l50*l30 - l51*l31 - l52*l32)*i3;
        float l44 = sqrtf(r4[4] - l40*l40 - l41*l41 - l42*l42 - l43*l43); float i4 = 1.f / l44;
        float l54 = (r5[4] - l50*l40 - l51*l41 - l52*l42 - l53*l43)*i4;
        float l55 = sqrtf(r5[5] - l50*l50 - l51*l51 - l52*l52 - l53*l53 - l54*l54);
        float i5 = 1.f / l55;

        float y0 =  ppct[0]*i0;
        float y1 = (ppct[1] - l10*y0)*i1;
        float y2 = (ppct[2] - l20*y0 - l21*y1)*i2;
        float y3 = (ppct[3] - l30*y0 - l31*y1 - l32*y2)*i3;
        float y4 = (ppct[4] - l40*y0 - l41*y1 - l42*y2 - l43*y3)*i4;
        float y5 = (ppct[5] - l50*y0 - l51*y1 - l52*y2 - l53*y3 - l54*y4)*i5;
        kk[5] =  y5*i5;
        kk[4] = (y4 - l54*kk[5])*i4;
        kk[3] = (y3 - l43*kk[4] - l53*kk[5])*i3;
        kk[2] = (y2 - l32*kk[3] - l42*kk[4] - l52*kk[5])*i2;
        kk[1] = (y1 - l21*kk[2] - l31*kk[3] - l41*kk[4] - l51*kk[5])*i1;
        kk[0] = (y0 - l10*kk[1] - l20*kk[2] - l30*kk[3] - l40*kk[4] - l50*kk[5])*i0;
    }
    FENCE();
    if (h == 0 && r < 15) wpk6(L + OFF_KB + 4 * r, kk);    // K bf16 rows
    FENCE();
    {   // xp += K e  (ev fp32 staged in OFF_VX)
        float e6[6]; rd6(L + OFF_VX, e6);
        xp += kk[0]*e6[0] + kk[1]*e6[1] + kk[2]*e6[2]
            + kk[3]*e6[3] + kk[4]*e6[4] + kk[5]*e6[5];
    }

    // ===== phase 4: T3 = Pp - K*PpCt^T; Pn = T3 + (K*R - T3*C^T)*K^T ======
    float pn8[8];
    {
        float t38[8];
        #define T3J(j) do { float pr[6]; unpk6(ldu4(L + OFF_PK + 4*min(j0 + (j), 14)), pr); \
            t38[(j)] = pp8[(j)] - (kk[0]*pr[0]+kk[1]*pr[1]+kk[2]*pr[2] \
                                  +kk[3]*pr[3]+kk[4]*pr[4]+kk[5]*pr[5]); } while(0)
        T3J(0); T3J(1); T3J(2); T3J(3);
        T3J(4); T3J(5); T3J(6); T3J(7);
        if (j0 + 7 >= 15) t38[7] = 0.f;

        float w[6];
        #define GJ(c) do { float cc[8]; unpk8(ldu4(L + OFF_CB + (c)*8 + 4*h), cc); \
            w[(c)] = cc[0]*t38[0]+cc[1]*t38[1]+cc[2]*t38[2]+cc[3]*t38[3] \
                   + cc[4]*t38[4]+cc[5]*t38[5]+cc[6]*t38[6]+cc[7]*t38[7]; } while(0)
        GJ(0); GJ(1); GJ(2); GJ(3); GJ(4); GJ(5);
        #pragma unroll
        for (int c = 0; c < 6; ++c) w[c] = -(w[c] + XOR16(w[c]));

        #define KRK(k) do { float rk[6]; unpk6(ldu4(L + OFF_RB + 4*(k)), rk); \
            w[0]+=kk[(k)]*rk[0]; w[1]+=kk[(k)]*rk[1]; w[2]+=kk[(k)]*rk[2]; \
            w[3]+=kk[(k)]*rk[3]; w[4]+=kk[(k)]*rk[4]; w[5]+=kk[(k)]*rk[5]; } while(0)
        KRK(0); KRK(1); KRK(2); KRK(3); KRK(4); KRK(5);

        #define PNJ(j) do { float krow[6]; unpk6(ldu4(L + OFF_KB + 4*min(j0 + (j), 14)), krow); \
            pn8[(j)] = t38[(j)] + (w[0]*krow[0]+w[1]*krow[1]+w[2]*krow[2] \
                                  +w[3]*krow[3]+w[4]*krow[4]+w[5]*krow[5]); } while(0)
        PNJ(0); PNJ(1); PNJ(2); PNJ(3);
        PNJ(4); PNJ(5); PNJ(6); PNJ(7);
        if (j0 + 7 >= 15) pn8[7] = 0.f;
    }

    // ---- stage results: Pn -> M1 (fp32), xp -> PK dw3 ----
    FENCE();
    if (r < 15) {
        wrow8(L + OFF_M1 + rc * 20 + j0, pn8);
        if (h == 0) L[OFF_PK + 4 * r + 3] = xp;
    }
    FENCE();

    // ---- coalesced stores (unrolled: LDS reads pipelined, then stores) ----
    {
        float* gpn = o_Pn + (size_t)ib0 * 225;
        float sP[8];
        #pragma unroll
        for (int t = 0; t < 8; ++t) {
            int i = min(tid + t * 64, 449);
            int it = i / 225, idx = i - it * 225;
            int rw = idx / 15, j = idx - rw * 15;
            sP[t] = lds[it * STR + OFF_M1 + rw * 20 + j];
        }
        #pragma unroll
        for (int t = 0; t < 8; ++t) {
            int i = tid + t * 64;
            if (i < limPA) gpn[i] = sP[t];
        }
        float* gxp = o_xp + (size_t)ib0 * 15;
        if (tid < limS) {
            int it = tid / 15, rw = tid - it * 15;
            gxp[tid] = lds[it * STR + OFF_PK + 4 * rw + 3];
        }
    }
}

extern "C" void kernel_launch(void* const* d_in, const int* in_sizes, int n_in,
                              void* d_out, int out_size, void* d_ws, size_t ws_size,
                              hipStream_t stream) {
    const float* g_state = (const float*)d_in[0];
    const float* g_obs   = (const float*)d_in[1];
    const float* g_u     = (const float*)d_in[2];
    const float* g_P     = (const float*)d_in[3];
    const float* g_A     = (const float*)d_in[4];
    const float* g_B     = (const float*)d_in[5];
    const float* g_C     = (const float*)d_in[6];
    const float* g_D     = (const float*)d_in[7];
    const float* g_c1    = (const float*)d_in[8];
    const float* g_c2    = (const float*)d_in[9];
    const float* g_Q     = (const float*)d_in[10];
    const float* g_R     = (const float*)d_in[11];

    const int bn = in_sizes[0] / 15;
    float* o_xp = (float*)d_out;
    float* o_pn = o_xp + (size_t)bn * 15;

    const int blocks = (bn + 1) / 2;   // 2 items per 64-thread (1-wave) block
    ekf_kernel<<<blocks, 64, 0, stream>>>(
        g_state, g_obs, g_u, g_P, g_A, g_B, g_C, g_D, g_c1, g_c2, g_Q, g_R,
        o_xp, o_pn, bn);
}